// Round 1
// baseline (743.987 us; speedup 1.0000x reference)
//
#include <hip/hip_runtime.h>
#include <hip/hip_bf16.h>
#include <math.h>

#define LYR 8
#define SEQ 4096
#define DIM 2048
#define NH 16
#define NKVH 2
#define HD 128
#define NQ 32
#define NKV 256   // KVH*HD
#define NQE 2048  // H*HD

// workspace layout (in floats)
#define WS_INVRMS 0
#define WS_COS (WS_INVRMS + LYR*SEQ)          // + 32768
#define WS_SIN (WS_COS + SEQ*HD)              // + 524288
#define WS_K   (WS_SIN + SEQ*HD)              // + 524288
#define WS_QB  (WS_K + (size_t)LYR*SEQ*NKV)   // + 8388608
// total ~ 9,994,240 floats = ~40 MB

// ---------------- kernel 1: inv_rms per (l,s) row ----------------
__global__ __launch_bounds__(256) void rms_kernel(const float* __restrict__ hs,
                                                  float* __restrict__ inv_rms) {
  int s = blockIdx.x, l = blockIdx.y, t = threadIdx.x;
  const float* row = hs + ((size_t)l * SEQ + s) * DIM;
  float4 v0 = *(const float4*)(row + t * 4);
  float4 v1 = *(const float4*)(row + t * 4 + 1024);
  float acc = v0.x*v0.x + v0.y*v0.y + v0.z*v0.z + v0.w*v0.w
            + v1.x*v1.x + v1.y*v1.y + v1.z*v1.z + v1.w*v1.w;
  #pragma unroll
  for (int off = 32; off >= 1; off >>= 1) acc += __shfl_down(acc, off);
  __shared__ float red[4];
  if ((t & 63) == 0) red[t >> 6] = acc;
  __syncthreads();
  if (t == 0) {
    float tot = red[0] + red[1] + red[2] + red[3];
    inv_rms[l * SEQ + s] = rsqrtf(tot / (float)DIM + 1e-6f);
  }
}

// ---------------- kernel 2: mrope cos/sin tables [S][HD] ----------------
__global__ void cossin_kernel(const int* __restrict__ pos_ids,
                              float* __restrict__ cost, float* __restrict__ sint) {
  int idx = blockIdx.x * 256 + threadIdx.x;  // S*HD
  int s = idx >> 7, d = idx & 127;
  int t = (d < 32) ? 0 : (d < 80 ? 1 : 2);   // mrope section -> position component
  int j = d & 63;
  double invf = pow(1000000.0, -(double)j / 64.0);
  double ph = (double)pos_ids[t * SEQ + s] * invf;
  cost[idx] = (float)cos(ph);
  sint[idx] = (float)sin(ph);
}

// ---------------- kernel 3: K projection GEMM (fused RMSNorm scale + bias) ----------------
// per layer: M=4096 (BM=64), N=256 (BN=256 full), K=2048 (BK=16); 256 thr, 8x8/thread
__global__ __launch_bounds__(256) void kgemm_kernel(
    const float* __restrict__ hs, const float* __restrict__ ln_w,
    const float* __restrict__ k_w, const float* __restrict__ k_b,
    const float* __restrict__ inv_rms, float* __restrict__ Kbuf) {
  __shared__ float As[16][68];    // [k][m] transposed
  __shared__ float Bs[16][260];   // [k][n]
  int t = threadIdx.x;
  int s0 = blockIdx.x * 64;
  int l = blockIdx.y;
  int tx = t & 31, ty = t >> 5;
  int ar = t >> 2, ac4 = (t & 3) * 4;
  float ir = inv_rms[l * SEQ + s0 + ar];
  const float* hrow = hs + ((size_t)l * SEQ + s0 + ar) * DIM;
  const float* lwl = ln_w + l * DIM;
  const float* kwl = k_w + (size_t)l * DIM * NKV;
  float acc[8][8];
  #pragma unroll
  for (int i = 0; i < 8; ++i)
    #pragma unroll
    for (int j = 0; j < 8; ++j) acc[i][j] = 0.f;

  for (int kb = 0; kb < DIM / 16; ++kb) {
    float4 av = *(const float4*)(hrow + kb * 16 + ac4);
    float4 lw = *(const float4*)(lwl + kb * 16 + ac4);
    As[ac4 + 0][ar] = av.x * ir * lw.x;
    As[ac4 + 1][ar] = av.y * ir * lw.y;
    As[ac4 + 2][ar] = av.z * ir * lw.z;
    As[ac4 + 3][ar] = av.w * ir * lw.w;
    #pragma unroll
    for (int i = 0; i < 4; ++i) {
      int idx = t * 4 + i * 1024;
      int br = idx >> 8, bc = idx & 255;
      *(float4*)&Bs[br][bc] = *(const float4*)(kwl + (size_t)(kb * 16 + br) * NKV + bc);
    }
    __syncthreads();
    #pragma unroll
    for (int kk = 0; kk < 16; ++kk) {
      float4 a0 = *(const float4*)&As[kk][ty * 4];
      float4 a1 = *(const float4*)&As[kk][ty * 4 + 32];
      float4 b0 = *(const float4*)&Bs[kk][tx * 4];
      float4 b1 = *(const float4*)&Bs[kk][tx * 4 + 128];
      float a_[8] = {a0.x, a0.y, a0.z, a0.w, a1.x, a1.y, a1.z, a1.w};
      float b_[8] = {b0.x, b0.y, b0.z, b0.w, b1.x, b1.y, b1.z, b1.w};
      #pragma unroll
      for (int i = 0; i < 8; ++i)
        #pragma unroll
        for (int j = 0; j < 8; ++j) acc[i][j] += a_[i] * b_[j];
    }
    __syncthreads();
  }
  float4 bi0 = *(const float4*)(k_b + l * NKV + tx * 4);
  float4 bi1 = *(const float4*)(k_b + l * NKV + 128 + tx * 4);
  #pragma unroll
  for (int i = 0; i < 8; ++i) {
    int row = (i < 4) ? (ty * 4 + i) : (32 + ty * 4 + i - 4);
    float* orow = Kbuf + ((size_t)l * SEQ + s0 + row) * NKV;
    float4 c0 = make_float4(acc[i][0] + bi0.x, acc[i][1] + bi0.y,
                            acc[i][2] + bi0.z, acc[i][3] + bi0.w);
    float4 c1 = make_float4(acc[i][4] + bi1.x, acc[i][5] + bi1.y,
                            acc[i][6] + bi1.z, acc[i][7] + bi1.w);
    *(float4*)(orow + tx * 4) = c0;
    *(float4*)(orow + 128 + tx * 4) = c1;
  }
}

// ---------------- kernel 4: RoPE on K, in place ----------------
__global__ void ropek_kernel(float* __restrict__ Kbuf, const float* __restrict__ cost,
                             const float* __restrict__ sint) {
  int idx = blockIdx.x * 256 + threadIdx.x;  // L*S*KVH*64
  int j = idx & 63;
  int kv = (idx >> 6) & 1;
  int s = (idx >> 7) & (SEQ - 1);
  int l = idx >> 19;
  float* row = Kbuf + ((size_t)l * SEQ + s) * NKV + kv * HD;
  const float* ct = cost + s * HD;
  const float* st = sint + s * HD;
  float lo = row[j], hi = row[j + 64];
  row[j]      = lo * ct[j]      - hi * st[j];
  row[j + 64] = hi * ct[j + 64] + lo * st[j + 64];
}

// ---------------- kernel 5: Q projection (M=32) + bias + RoPE ----------------
// grid (h, l); BN=128 = exactly one head; BK=16
__global__ __launch_bounds__(256) void qgemm_kernel(
    const float* __restrict__ hs, const float* __restrict__ ln_w,
    const float* __restrict__ q_w, const float* __restrict__ q_b,
    const int* __restrict__ q_idx, const float* __restrict__ inv_rms,
    const float* __restrict__ cost, const float* __restrict__ sint,
    float* __restrict__ Qbuf) {
  __shared__ float Aq[16][36];   // [k][m]
  __shared__ float Bs[16][132];  // [k][n]
  __shared__ float Ct[32][132];
  __shared__ int qix[32];
  __shared__ float qir[32];
  int t = threadIdx.x;
  int h = blockIdx.x, l = blockIdx.y;
  if (t < 32) {
    int qi = q_idx[t];
    qix[t] = qi;
    qir[t] = inv_rms[l * SEQ + qi];
  }
  __syncthreads();
  int tx = t & 31, ty = t >> 5;
  int aqi = t >> 3, ac2 = (t & 7) * 2;
  float acc[4][4];
  #pragma unroll
  for (int i = 0; i < 4; ++i)
    #pragma unroll
    for (int j = 0; j < 4; ++j) acc[i][j] = 0.f;

  int qrow = qix[aqi];
  float irv = qir[aqi];
  const float* hp0 = hs + ((size_t)l * SEQ + qrow) * DIM;
  const float* lwl = ln_w + l * DIM;
  const float* qwl = q_w + (size_t)l * DIM * NQE + h * HD;

  for (int kb = 0; kb < DIM / 16; ++kb) {
    float2 hv = *(const float2*)(hp0 + kb * 16 + ac2);
    float2 lw = *(const float2*)(lwl + kb * 16 + ac2);
    Aq[ac2 + 0][aqi] = hv.x * irv * lw.x;
    Aq[ac2 + 1][aqi] = hv.y * irv * lw.y;
    #pragma unroll
    for (int i = 0; i < 2; ++i) {
      int idx = t * 4 + i * 1024;
      int br = idx >> 7, bc = idx & 127;
      *(float4*)&Bs[br][bc] = *(const float4*)(qwl + (size_t)(kb * 16 + br) * NQE + bc);
    }
    __syncthreads();
    #pragma unroll
    for (int kk = 0; kk < 16; ++kk) {
      float4 a = *(const float4*)&Aq[kk][ty * 4];
      float4 b = *(const float4*)&Bs[kk][tx * 4];
      float a_[4] = {a.x, a.y, a.z, a.w};
      float b_[4] = {b.x, b.y, b.z, b.w};
      #pragma unroll
      for (int i = 0; i < 4; ++i)
        #pragma unroll
        for (int j = 0; j < 4; ++j) acc[i][j] += a_[i] * b_[j];
    }
    __syncthreads();
  }
  float4 qb = *(const float4*)(q_b + l * NQE + h * HD + tx * 4);
  #pragma unroll
  for (int i = 0; i < 4; ++i) {
    float4 c = make_float4(acc[i][0] + qb.x, acc[i][1] + qb.y,
                           acc[i][2] + qb.z, acc[i][3] + qb.w);
    *(float4*)&Ct[ty * 4 + i][tx * 4] = c;
  }
  __syncthreads();
  // rope + write: 32 rows x 64 pairs
  #pragma unroll
  for (int rep = 0; rep < 8; ++rep) {
    int p = t + rep * 256;
    int r = p >> 6, j = p & 63;
    float lo = Ct[r][j], hi = Ct[r][j + 64];
    int sp = qix[r];
    const float* ct = cost + sp * HD;
    const float* st = sint + sp * HD;
    float* qo = Qbuf + (((size_t)l * NH + h) * NQ + r) * HD;
    qo[j]      = lo * ct[j]      - hi * st[j];
    qo[j + 64] = hi * ct[j + 64] + lo * st[j + 64];
  }
}

// ---------------- kernel 6: scores = scale * Q.K^T + mask ----------------
// grid (keychunk=32, h=16, l=8); block computes 32 q x 128 keys
__global__ __launch_bounds__(256) void scores_kernel(
    const float* __restrict__ Qbuf, const float* __restrict__ Kbuf,
    const int* __restrict__ q_idx, float* __restrict__ out) {
  __shared__ float Qt[128][36];  // [d][q]
  __shared__ float Kt[32][132];  // [d][key]
  int t = threadIdx.x;
  int kc = blockIdx.x;
  int h = blockIdx.y, l = blockIdx.z;
  int kv = h >> 3;
  int s0 = kc * 128;
  const float* qbase = Qbuf + ((size_t)l * NH + h) * NQ * HD;
  #pragma unroll
  for (int i = 0; i < 4; ++i) {
    int idx = t * 4 + i * 1024;
    int qi = idx >> 7, d = idx & 127;
    float4 v = *(const float4*)(qbase + idx);
    Qt[d + 0][qi] = v.x; Qt[d + 1][qi] = v.y;
    Qt[d + 2][qi] = v.z; Qt[d + 3][qi] = v.w;
  }
  float acc[4][4];
  #pragma unroll
  for (int i = 0; i < 4; ++i)
    #pragma unroll
    for (int j = 0; j < 4; ++j) acc[i][j] = 0.f;
  int tx = t & 31, ty = t >> 5;
  for (int dc = 0; dc < 4; ++dc) {
    __syncthreads();  // Qt ready (dc=0) / previous compute done
    #pragma unroll
    for (int i = 0; i < 4; ++i) {
      int idx = t * 4 + i * 1024;
      int key = idx >> 5, dd = idx & 31;
      float4 v = *(const float4*)(Kbuf + ((size_t)l * SEQ + s0 + key) * NKV + kv * HD + dc * 32 + dd);
      Kt[dd + 0][key] = v.x; Kt[dd + 1][key] = v.y;
      Kt[dd + 2][key] = v.z; Kt[dd + 3][key] = v.w;
    }
    __syncthreads();
    #pragma unroll
    for (int dd = 0; dd < 32; ++dd) {
      float4 a = *(const float4*)&Qt[dc * 32 + dd][ty * 4];
      float4 b = *(const float4*)&Kt[dd][tx * 4];
      float a_[4] = {a.x, a.y, a.z, a.w};
      float b_[4] = {b.x, b.y, b.z, b.w};
      #pragma unroll
      for (int i = 0; i < 4; ++i)
        #pragma unroll
        for (int j = 0; j < 4; ++j) acc[i][j] += a_[i] * b_[j];
    }
  }
  const float scale = 0.088388347648318447f;  // 1/sqrt(128)
  #pragma unroll
  for (int i = 0; i < 4; ++i) {
    int qy = ty * 4 + i;
    int qiv = q_idx[qy];
    int sb = s0 + tx * 4;
    float4 v;
    v.x = (sb + 0 > qiv) ? -1e9f : acc[i][0] * scale;
    v.y = (sb + 1 > qiv) ? -1e9f : acc[i][1] * scale;
    v.z = (sb + 2 > qiv) ? -1e9f : acc[i][2] * scale;
    v.w = (sb + 3 > qiv) ? -1e9f : acc[i][3] * scale;
    *(float4*)(out + (((size_t)l * NH + h) * NQ + qy) * SEQ + sb) = v;
  }
}

// ---------------- kernel 7: row softmax over S ----------------
__global__ __launch_bounds__(256) void softmax_kernel(float* __restrict__ out) {
  size_t row = blockIdx.x;
  float* p = out + row * SEQ;
  int t = threadIdx.x;
  float4 v[4];
  float mx = -1e30f;
  #pragma unroll
  for (int i = 0; i < 4; ++i) {
    v[i] = *(const float4*)(p + t * 4 + i * 1024);
    mx = fmaxf(mx, fmaxf(fmaxf(v[i].x, v[i].y), fmaxf(v[i].z, v[i].w)));
  }
  #pragma unroll
  for (int off = 32; off >= 1; off >>= 1) mx = fmaxf(mx, __shfl_xor(mx, off));
  __shared__ float red[4];
  if ((t & 63) == 0) red[t >> 6] = mx;
  __syncthreads();
  mx = fmaxf(fmaxf(red[0], red[1]), fmaxf(red[2], red[3]));
  __syncthreads();
  float sum = 0.f;
  #pragma unroll
  for (int i = 0; i < 4; ++i) {
    v[i].x = __expf(v[i].x - mx); v[i].y = __expf(v[i].y - mx);
    v[i].z = __expf(v[i].z - mx); v[i].w = __expf(v[i].w - mx);
    sum += v[i].x + v[i].y + v[i].z + v[i].w;
  }
  #pragma unroll
  for (int off = 32; off >= 1; off >>= 1) sum += __shfl_xor(sum, off);
  if ((t & 63) == 0) red[t >> 6] = sum;
  __syncthreads();
  sum = red[0] + red[1] + red[2] + red[3];
  float inv = 1.f / sum;
  #pragma unroll
  for (int i = 0; i < 4; ++i) {
    v[i].x *= inv; v[i].y *= inv; v[i].z *= inv; v[i].w *= inv;
    *(float4*)(p + t * 4 + i * 1024) = v[i];
  }
}

extern "C" void kernel_launch(void* const* d_in, const int* in_sizes, int n_in,
                              void* d_out, int out_size, void* d_ws, size_t ws_size,
                              hipStream_t stream) {
  const float* hs   = (const float*)d_in[0];
  const float* ln_w = (const float*)d_in[1];
  const float* q_w  = (const float*)d_in[2];
  const float* q_b  = (const float*)d_in[3];
  const float* k_w  = (const float*)d_in[4];
  const float* k_b  = (const float*)d_in[5];
  const int* pos    = (const int*)d_in[6];
  const int* qidx   = (const int*)d_in[7];
  float* out = (float*)d_out;
  float* ws = (float*)d_ws;
  float* inv_rms = ws + WS_INVRMS;
  float* cost = ws + WS_COS;
  float* sint = ws + WS_SIN;
  float* Kbuf = ws + WS_K;
  float* Qbuf = ws + WS_QB;

  rms_kernel<<<dim3(SEQ, LYR), 256, 0, stream>>>(hs, inv_rms);
  cossin_kernel<<<(SEQ * HD) / 256, 256, 0, stream>>>(pos, cost, sint);
  kgemm_kernel<<<dim3(SEQ / 64, LYR), 256, 0, stream>>>(hs, ln_w, k_w, k_b, inv_rms, Kbuf);
  ropek_kernel<<<(LYR * SEQ * 128) / 256, 256, 0, stream>>>(Kbuf, cost, sint);
  qgemm_kernel<<<dim3(NH, LYR), 256, 0, stream>>>(hs, ln_w, q_w, q_b, qidx, inv_rms, cost, sint, Qbuf);
  scores_kernel<<<dim3(SEQ / 128, NH, LYR), 256, 0, stream>>>(Qbuf, Kbuf, qidx, out);
  softmax_kernel<<<LYR * NH * NQ, 256, 0, stream>>>(out);
}

// Round 2
// 422.941 us; speedup vs baseline: 1.7591x; 1.7591x over previous
//
#include <hip/hip_runtime.h>
#include <hip/hip_bf16.h>
#include <math.h>

#define LYR 8
#define SEQ 4096
#define DIM 2048
#define NH 16
#define NKVH 2
#define HD 128
#define NQ 32
#define NKV 256   // KVH*HD
#define NQE 2048  // H*HD

typedef __attribute__((ext_vector_type(8))) short short8;
typedef __attribute__((ext_vector_type(4))) float f32x4;

// workspace layout (in float units)
#define WS_IRQ 0                               // L*NQ = 256
#define WS_COS (WS_IRQ + 256)                  // + 524288
#define WS_SIN (WS_COS + SEQ*HD)               // + 524288
#define WS_K   (WS_SIN + SEQ*HD)               // + 8388608
#define WS_QB  (WS_K + (size_t)LYR*SEQ*NKV)    // + 524288
#define WS_W2  (WS_QB + (size_t)LYR*NH*NQ*HD)  // + 5242880 floats (10485760 shorts)
// total ~ 58 MB

__device__ __forceinline__ short f2bf(float x) {
  __hip_bfloat16 h = __float2bfloat16(x);
  return *(short*)&h;
}
__device__ __forceinline__ float bf2f(short s) {
  unsigned u = ((unsigned)(unsigned short)s) << 16;
  return __uint_as_float(u);
}

// ---------------- kernel A: prep W' = ln_w * k_w, split bf16 hi/lo ----------------
// grid (64 kb, LYR); 256 thr; writes per-(l,kb) blob: [hi 256n x 40k][lo 256n x 40k] shorts
__global__ __launch_bounds__(256) void prep_kernel(
    const float* __restrict__ ln_w, const float* __restrict__ k_w,
    short* __restrict__ W2) {
  int kb = blockIdx.x, l = blockIdx.y, t = threadIdx.x;  // t = n
  const float* wp = k_w + (size_t)l * DIM * NKV + (size_t)(kb * 32) * NKV + t;
  const float* lnp = ln_w + l * DIM + kb * 32;
  short* blob = W2 + (size_t)(l * 64 + kb) * 20480;
  short hi[32], lo[32];
  #pragma unroll
  for (int k = 0; k < 32; ++k) {
    float v = lnp[k] * wp[(size_t)k * NKV];
    short h = f2bf(v);
    hi[k] = h;
    lo[k] = f2bf(v - bf2f(h));
  }
  #pragma unroll
  for (int g = 0; g < 4; ++g) {
    *(short8*)(blob + t * 40 + g * 8) = *(short8*)&hi[g * 8];
    *(short8*)(blob + 10240 + t * 40 + g * 8) = *(short8*)&lo[g * 8];
  }
}

// ---------------- kernel B: inv_rms for the 32 q rows only ----------------
__global__ __launch_bounds__(256) void rmsq_kernel(const float* __restrict__ hs,
                                                   const int* __restrict__ q_idx,
                                                   float* __restrict__ irq) {
  int qi = blockIdx.x, l = blockIdx.y, t = threadIdx.x;
  int s = q_idx[qi];
  const float* row = hs + ((size_t)l * SEQ + s) * DIM;
  float4 v0 = *(const float4*)(row + t * 4);
  float4 v1 = *(const float4*)(row + t * 4 + 1024);
  float acc = v0.x*v0.x + v0.y*v0.y + v0.z*v0.z + v0.w*v0.w
            + v1.x*v1.x + v1.y*v1.y + v1.z*v1.z + v1.w*v1.w;
  #pragma unroll
  for (int off = 32; off >= 1; off >>= 1) acc += __shfl_down(acc, off);
  __shared__ float red[4];
  if ((t & 63) == 0) red[t >> 6] = acc;
  __syncthreads();
  if (t == 0) {
    float tot = red[0] + red[1] + red[2] + red[3];
    irq[l * NQ + qi] = rsqrtf(tot / (float)DIM + 1e-6f);
  }
}

// ---------------- kernel C: mrope cos/sin tables [S][HD] ----------------
__global__ void cossin_kernel(const int* __restrict__ pos_ids,
                              float* __restrict__ cost, float* __restrict__ sint) {
  int idx = blockIdx.x * 256 + threadIdx.x;  // S*HD
  int s = idx >> 7, d = idx & 127;
  int t = (d < 32) ? 0 : (d < 80 ? 1 : 2);   // mrope section -> position component
  int j = d & 63;
  double invf = pow(1000000.0, -(double)j / 64.0);
  double ph = (double)pos_ids[t * SEQ + s] * invf;
  cost[idx] = (float)cos(ph);
  sint[idx] = (float)sin(ph);
}

// ---------------- kernel D: K projection via bf16x3 MFMA, fused RMSNorm + bias ----------------
// per layer: M=4096 (BM=64), N=256 (BN=256), K step 32; 256 thr (4 waves 2m x 2n)
__global__ __launch_bounds__(256) void kgemm_kernel(
    const float* __restrict__ hs, const short* __restrict__ W2,
    const float* __restrict__ k_b, float* __restrict__ Kbuf) {
  // LDS: A hi/lo [64][40] shorts each; B hi/lo [256][40] shorts each (B = blob image)
  __shared__ __align__(16) short As[2 * 64 * 40];    // 10240 B
  __shared__ __align__(1024) short Bs[2 * 256 * 40]; // 40960 B
  __shared__ float sqred[64][4];
  __shared__ float irs[64];

  int t = threadIdx.x;
  int s0 = blockIdx.x * 64;
  int l = blockIdx.y;
  int lane = t & 63, w = t >> 6;
  int wm = w & 1, wn = w >> 1;

  int arow = t >> 2;           // staging row (fixed per thread)
  int akq = (t & 3) * 8;       // staging k offset
  const float* hrow = hs + ((size_t)l * SEQ + s0 + arow) * DIM + akq;
  const short* blob0 = W2 + (size_t)l * 64 * 20480;

  f32x4 acc[2][8];
  #pragma unroll
  for (int m = 0; m < 2; ++m)
    #pragma unroll
    for (int fn = 0; fn < 8; ++fn) acc[m][fn] = (f32x4){0.f, 0.f, 0.f, 0.f};
  float sq = 0.f;

  int kg = lane >> 4;          // k-group for fragments
  int fr = lane & 15;          // row/col within fragment

  for (int kb = 0; kb < 64; ++kb) {
    // A: global fp32 loads (overlap previous MFMA)
    float4 a0 = *(const float4*)(hrow + kb * 32);
    float4 a1 = *(const float4*)(hrow + kb * 32 + 4);
    sq += a0.x*a0.x + a0.y*a0.y + a0.z*a0.z + a0.w*a0.w
        + a1.x*a1.x + a1.y*a1.y + a1.z*a1.z + a1.w*a1.w;
    float av[8] = {a0.x, a0.y, a0.z, a0.w, a1.x, a1.y, a1.z, a1.w};
    short hi8[8], lo8[8];
    #pragma unroll
    for (int j = 0; j < 8; ++j) {
      short h = f2bf(av[j]);
      hi8[j] = h;
      lo8[j] = f2bf(av[j] - bf2f(h));
    }
    __syncthreads();  // previous compute done reading LDS
    *(short8*)(As + arow * 40 + akq) = *(short8*)hi8;
    *(short8*)(As + 2560 + arow * 40 + akq) = *(short8*)lo8;
    // B: pure linear copy global->LDS, 40 chunks of 1024B, wave w does 10
    const char* bsrc = (const char*)(blob0 + (size_t)kb * 20480);
    #pragma unroll
    for (int c = 0; c < 10; ++c) {
      int chunk = w * 10 + c;
      __builtin_amdgcn_global_load_lds(
          (const __attribute__((address_space(1))) unsigned int*)(bsrc + chunk * 1024 + lane * 16),
          (__attribute__((address_space(3))) unsigned int*)((char*)Bs + chunk * 1024),
          16, 0, 0);
    }
    __syncthreads();  // staging visible (compiler drains vmcnt/lgkmcnt)

    short8 ah[2], al[2];
    #pragma unroll
    for (int m = 0; m < 2; ++m) {
      int r = wm * 32 + m * 16 + fr;
      ah[m] = *(const short8*)(As + r * 40 + kg * 8);
      al[m] = *(const short8*)(As + 2560 + r * 40 + kg * 8);
    }
    #pragma unroll
    for (int fn = 0; fn < 8; ++fn) {
      int n = wn * 128 + fn * 16 + fr;
      short8 bh = *(const short8*)(Bs + n * 40 + kg * 8);
      short8 bl = *(const short8*)(Bs + 10240 + n * 40 + kg * 8);
      #pragma unroll
      for (int m = 0; m < 2; ++m) {
        acc[m][fn] = __builtin_amdgcn_mfma_f32_16x16x32_bf16(ah[m], bh, acc[m][fn], 0, 0, 0);
        acc[m][fn] = __builtin_amdgcn_mfma_f32_16x16x32_bf16(ah[m], bl, acc[m][fn], 0, 0, 0);
        acc[m][fn] = __builtin_amdgcn_mfma_f32_16x16x32_bf16(al[m], bh, acc[m][fn], 0, 0, 0);
      }
    }
  }

  // inv_rms reduction (each thread owns row arow's k-slice)
  __syncthreads();
  sqred[arow][t & 3] = sq;
  __syncthreads();
  if ((t & 3) == 0) {
    float tot = sqred[arow][0] + sqred[arow][1] + sqred[arow][2] + sqred[arow][3];
    irs[arow] = rsqrtf(tot / (float)DIM + 1e-6f);
  }
  __syncthreads();

  // epilogue: C[row][col] = acc * ir[row] + k_b[col]
  int rbase = wm * 32 + (kg << 2);
  int cbase = wn * 128 + fr;
  float bias[8];
  #pragma unroll
  for (int fn = 0; fn < 8; ++fn) bias[fn] = k_b[l * NKV + cbase + fn * 16];
  #pragma unroll
  for (int m = 0; m < 2; ++m) {
    #pragma unroll
    for (int r = 0; r < 4; ++r) {
      int row = rbase + m * 16 + r;
      float ir = irs[row];
      float* orow = Kbuf + ((size_t)l * SEQ + s0 + row) * NKV;
      #pragma unroll
      for (int fn = 0; fn < 8; ++fn)
        orow[cbase + fn * 16] = acc[m][fn][r] * ir + bias[fn];
    }
  }
}

// ---------------- kernel E: RoPE on K, in place ----------------
__global__ void ropek_kernel(float* __restrict__ Kbuf, const float* __restrict__ cost,
                             const float* __restrict__ sint) {
  int idx = blockIdx.x * 256 + threadIdx.x;  // L*S*KVH*64
  int j = idx & 63;
  int kv = (idx >> 6) & 1;
  int s = (idx >> 7) & (SEQ - 1);
  int l = idx >> 19;
  float* row = Kbuf + ((size_t)l * SEQ + s) * NKV + kv * HD;
  const float* ct = cost + s * HD;
  const float* st = sint + s * HD;
  float lo = row[j], hi = row[j + 64];
  row[j]      = lo * ct[j]      - hi * st[j];
  row[j + 64] = hi * ct[j + 64] + lo * st[j + 64];
}

// ---------------- kernel F: Q projection (M=32) + bias + RoPE ----------------
// grid (h, l); BN=128 = exactly one head; BK=16
__global__ __launch_bounds__(256) void qgemm_kernel(
    const float* __restrict__ hs, const float* __restrict__ ln_w,
    const float* __restrict__ q_w, const float* __restrict__ q_b,
    const int* __restrict__ q_idx, const float* __restrict__ irq,
    const float* __restrict__ cost, const float* __restrict__ sint,
    float* __restrict__ Qbuf) {
  __shared__ float Aq[16][36];   // [k][m]
  __shared__ float Bs[16][132];  // [k][n]
  __shared__ float Ct[32][132];
  __shared__ int qix[32];
  __shared__ float qir[32];
  int t = threadIdx.x;
  int h = blockIdx.x, l = blockIdx.y;
  if (t < 32) {
    qix[t] = q_idx[t];
    qir[t] = irq[l * NQ + t];
  }
  __syncthreads();
  int tx = t & 31, ty = t >> 5;
  int aqi = t >> 3, ac2 = (t & 7) * 2;
  float acc[4][4];
  #pragma unroll
  for (int i = 0; i < 4; ++i)
    #pragma unroll
    for (int j = 0; j < 4; ++j) acc[i][j] = 0.f;

  int qrow = qix[aqi];
  float irv = qir[aqi];
  const float* hp0 = hs + ((size_t)l * SEQ + qrow) * DIM;
  const float* lwl = ln_w + l * DIM;
  const float* qwl = q_w + (size_t)l * DIM * NQE + h * HD;

  for (int kb = 0; kb < DIM / 16; ++kb) {
    float2 hv = *(const float2*)(hp0 + kb * 16 + ac2);
    float2 lw = *(const float2*)(lwl + kb * 16 + ac2);
    Aq[ac2 + 0][aqi] = hv.x * irv * lw.x;
    Aq[ac2 + 1][aqi] = hv.y * irv * lw.y;
    #pragma unroll
    for (int i = 0; i < 2; ++i) {
      int idx = t * 4 + i * 1024;
      int br = idx >> 7, bc = idx & 127;
      *(float4*)&Bs[br][bc] = *(const float4*)(qwl + (size_t)(kb * 16 + br) * NQE + bc);
    }
    __syncthreads();
    #pragma unroll
    for (int kk = 0; kk < 16; ++kk) {
      float4 a = *(const float4*)&Aq[kk][ty * 4];
      float4 b = *(const float4*)&Bs[kk][tx * 4];
      float a_[4] = {a.x, a.y, a.z, a.w};
      float b_[4] = {b.x, b.y, b.z, b.w};
      #pragma unroll
      for (int i = 0; i < 4; ++i)
        #pragma unroll
        for (int j = 0; j < 4; ++j) acc[i][j] += a_[i] * b_[j];
    }
    __syncthreads();
  }
  float4 qb = *(const float4*)(q_b + l * NQE + h * HD + tx * 4);
  #pragma unroll
  for (int i = 0; i < 4; ++i) {
    float4 c = make_float4(acc[i][0] + qb.x, acc[i][1] + qb.y,
                           acc[i][2] + qb.z, acc[i][3] + qb.w);
    *(float4*)&Ct[ty * 4 + i][tx * 4] = c;
  }
  __syncthreads();
  // rope + write: 32 rows x 64 pairs
  #pragma unroll
  for (int rep = 0; rep < 8; ++rep) {
    int p = t + rep * 256;
    int r = p >> 6, j = p & 63;
    float lo = Ct[r][j], hi = Ct[r][j + 64];
    int sp = qix[r];
    const float* ct = cost + sp * HD;
    const float* st = sint + sp * HD;
    float* qo = Qbuf + (((size_t)l * NH + h) * NQ + r) * HD;
    qo[j]      = lo * ct[j]      - hi * st[j];
    qo[j + 64] = hi * ct[j + 64] + lo * st[j + 64];
  }
}

// ---------------- kernel G: scores = scale * Q.K^T + mask ----------------
// grid (keychunk=32, h=16, l=8); block computes 32 q x 128 keys
__global__ __launch_bounds__(256) void scores_kernel(
    const float* __restrict__ Qbuf, const float* __restrict__ Kbuf,
    const int* __restrict__ q_idx, float* __restrict__ out) {
  __shared__ float Qt[128][36];  // [d][q]
  __shared__ float Kt[32][132];  // [d][key]
  int t = threadIdx.x;
  int kc = blockIdx.x;
  int h = blockIdx.y, l = blockIdx.z;
  int kv = h >> 3;
  int s0 = kc * 128;
  const float* qbase = Qbuf + ((size_t)l * NH + h) * NQ * HD;
  #pragma unroll
  for (int i = 0; i < 4; ++i) {
    int idx = t * 4 + i * 1024;
    int qi = idx >> 7, d = idx & 127;
    float4 v = *(const float4*)(qbase + idx);
    Qt[d + 0][qi] = v.x; Qt[d + 1][qi] = v.y;
    Qt[d + 2][qi] = v.z; Qt[d + 3][qi] = v.w;
  }
  float acc[4][4];
  #pragma unroll
  for (int i = 0; i < 4; ++i)
    #pragma unroll
    for (int j = 0; j < 4; ++j) acc[i][j] = 0.f;
  int tx = t & 31, ty = t >> 5;
  for (int dc = 0; dc < 4; ++dc) {
    __syncthreads();  // Qt ready (dc=0) / previous compute done
    #pragma unroll
    for (int i = 0; i < 4; ++i) {
      int idx = t * 4 + i * 1024;
      int key = idx >> 5, dd = idx & 31;
      float4 v = *(const float4*)(Kbuf + ((size_t)l * SEQ + s0 + key) * NKV + kv * HD + dc * 32 + dd);
      Kt[dd + 0][key] = v.x; Kt[dd + 1][key] = v.y;
      Kt[dd + 2][key] = v.z; Kt[dd + 3][key] = v.w;
    }
    __syncthreads();
    #pragma unroll
    for (int dd = 0; dd < 32; ++dd) {
      float4 a = *(const float4*)&Qt[dc * 32 + dd][ty * 4];
      float4 b = *(const float4*)&Kt[dd][tx * 4];
      float a_[4] = {a.x, a.y, a.z, a.w};
      float b_[4] = {b.x, b.y, b.z, b.w};
      #pragma unroll
      for (int i = 0; i < 4; ++i)
        #pragma unroll
        for (int j = 0; j < 4; ++j) acc[i][j] += a_[i] * b_[j];
    }
  }
  const float scale = 0.088388347648318447f;  // 1/sqrt(128)
  #pragma unroll
  for (int i = 0; i < 4; ++i) {
    int qy = ty * 4 + i;
    int qiv = q_idx[qy];
    int sb = s0 + tx * 4;
    float4 v;
    v.x = (sb + 0 > qiv) ? -1e9f : acc[i][0] * scale;
    v.y = (sb + 1 > qiv) ? -1e9f : acc[i][1] * scale;
    v.z = (sb + 2 > qiv) ? -1e9f : acc[i][2] * scale;
    v.w = (sb + 3 > qiv) ? -1e9f : acc[i][3] * scale;
    *(float4*)(out + (((size_t)l * NH + h) * NQ + qy) * SEQ + sb) = v;
  }
}

// ---------------- kernel H: row softmax over S ----------------
__global__ __launch_bounds__(256) void softmax_kernel(float* __restrict__ out) {
  size_t row = blockIdx.x;
  float* p = out + row * SEQ;
  int t = threadIdx.x;
  float4 v[4];
  float mx = -1e30f;
  #pragma unroll
  for (int i = 0; i < 4; ++i) {
    v[i] = *(const float4*)(p + t * 4 + i * 1024);
    mx = fmaxf(mx, fmaxf(fmaxf(v[i].x, v[i].y), fmaxf(v[i].z, v[i].w)));
  }
  #pragma unroll
  for (int off = 32; off >= 1; off >>= 1) mx = fmaxf(mx, __shfl_xor(mx, off));
  __shared__ float red[4];
  if ((t & 63) == 0) red[t >> 6] = mx;
  __syncthreads();
  mx = fmaxf(fmaxf(red[0], red[1]), fmaxf(red[2], red[3]));
  __syncthreads();
  float sum = 0.f;
  #pragma unroll
  for (int i = 0; i < 4; ++i) {
    v[i].x = __expf(v[i].x - mx); v[i].y = __expf(v[i].y - mx);
    v[i].z = __expf(v[i].z - mx); v[i].w = __expf(v[i].w - mx);
    sum += v[i].x + v[i].y + v[i].z + v[i].w;
  }
  #pragma unroll
  for (int off = 32; off >= 1; off >>= 1) sum += __shfl_xor(sum, off);
  if ((t & 63) == 0) red[t >> 6] = sum;
  __syncthreads();
  sum = red[0] + red[1] + red[2] + red[3];
  float inv = 1.f / sum;
  #pragma unroll
  for (int i = 0; i < 4; ++i) {
    v[i].x *= inv; v[i].y *= inv; v[i].z *= inv; v[i].w *= inv;
    *(float4*)(p + t * 4 + i * 1024) = v[i];
  }
}

extern "C" void kernel_launch(void* const* d_in, const int* in_sizes, int n_in,
                              void* d_out, int out_size, void* d_ws, size_t ws_size,
                              hipStream_t stream) {
  const float* hs   = (const float*)d_in[0];
  const float* ln_w = (const float*)d_in[1];
  const float* q_w  = (const float*)d_in[2];
  const float* q_b  = (const float*)d_in[3];
  const float* k_w  = (const float*)d_in[4];
  const float* k_b  = (const float*)d_in[5];
  const int* pos    = (const int*)d_in[6];
  const int* qidx   = (const int*)d_in[7];
  float* out = (float*)d_out;
  float* ws = (float*)d_ws;
  float* irq  = ws + WS_IRQ;
  float* cost = ws + WS_COS;
  float* sint = ws + WS_SIN;
  float* Kbuf = ws + WS_K;
  float* Qbuf = ws + WS_QB;
  short* W2   = (short*)(ws + WS_W2);

  prep_kernel<<<dim3(64, LYR), 256, 0, stream>>>(ln_w, k_w, W2);
  rmsq_kernel<<<dim3(NQ, LYR), 256, 0, stream>>>(hs, qidx, irq);
  cossin_kernel<<<(SEQ * HD) / 256, 256, 0, stream>>>(pos, cost, sint);
  kgemm_kernel<<<dim3(SEQ / 64, LYR), 256, 0, stream>>>(hs, W2, k_b, Kbuf);
  ropek_kernel<<<(LYR * SEQ * 128) / 256, 256, 0, stream>>>(Kbuf, cost, sint);
  qgemm_kernel<<<dim3(NH, LYR), 256, 0, stream>>>(hs, ln_w, q_w, q_b, qidx, irq, cost, sint, Qbuf);
  scores_kernel<<<dim3(SEQ / 128, NH, LYR), 256, 0, stream>>>(Qbuf, Kbuf, qidx, out);
  softmax_kernel<<<LYR * NH * NQ, 256, 0, stream>>>(out);
}

// Round 3
// 403.330 us; speedup vs baseline: 1.8446x; 1.0486x over previous
//
#include <hip/hip_runtime.h>
#include <hip/hip_bf16.h>
#include <math.h>

#define LYR 8
#define SEQ 4096
#define DIM 2048
#define NH 16
#define HD 128
#define NQ 32
#define NKV 256   // KVH*HD
#define NQE 2048  // H*HD

typedef __attribute__((ext_vector_type(8))) short short8;
typedef __attribute__((ext_vector_type(4))) float f32x4;

// workspace layout (float units)
#define WS_IRQ   0                        // 256
#define WS_XQT   256                      // 524288  xqT[l][k][32]
#define WS_COS   524544                   // 524288
#define WS_SIN   1048832                  // 524288
#define WS_QBUF  1573120                  // 524288  Qbuf fp32 [l][q][2048] (unroped)
#define WS_KBUF  2097408                  // 8388608 Kbuf fp32 [l][s][256] (roped)
#define WS_BIG   10486016                 // 8388608 floats = 32MB: W2 blob (16MB), then Kblob (32MB) overwrites after kgemm
#define WS_QBLOB 18874624                 // 524288  Qblob shorts
// end 19398912 floats ~ 77.6 MB

__device__ __forceinline__ short f2bf(float x) {
  __hip_bfloat16 h = __float2bfloat16(x);
  return *(short*)&h;
}
__device__ __forceinline__ float bf2f(short s) {
  unsigned u = ((unsigned)(unsigned short)s) << 16;
  return __uint_as_float(u);
}

#define GLOAD16(srcp, dstp) \
  __builtin_amdgcn_global_load_lds( \
      (const __attribute__((address_space(1))) unsigned int*)(srcp), \
      (__attribute__((address_space(3))) unsigned int*)(dstp), 16, 0, 0)

// ---------------- prep: W' = ln_w*k_w -> frag-lane-linear bf16 hi/lo blob ----------------
// blob per (l,kb): 16384 shorts = [hi: pos 0..1023][lo: pos 0..1023], pos=(f<<6)|lane
// content: W'[k = kb*32 + (lane>>4)*8 + e][n = f*16 + (lane&15)]
__global__ __launch_bounds__(256) void prep_kernel(
    const float* __restrict__ ln_w, const float* __restrict__ k_w,
    short* __restrict__ W2) {
  int kb = blockIdx.x, l = blockIdx.y, t = threadIdx.x;
  const float* kwl = k_w + (size_t)l * DIM * NKV;
  const float* lnl = ln_w + l * DIM;
  short* blob = W2 + (size_t)(l * 64 + kb) * 16384;
  #pragma unroll
  for (int i = 0; i < 4; ++i) {
    int p = t + i * 256;
    int fi = p >> 6, lane = p & 63;
    int n = fi * 16 + (lane & 15);
    int k0 = kb * 32 + (lane >> 4) * 8;
    short hi8[8], lo8[8];
    #pragma unroll
    for (int e = 0; e < 8; ++e) {
      float v = lnl[k0 + e] * kwl[(size_t)(k0 + e) * NKV + n];
      short h = f2bf(v);
      hi8[e] = h;
      lo8[e] = f2bf(v - bf2f(h));
    }
    *(short8*)(blob + p * 8) = *(short8*)hi8;
    *(short8*)(blob + 8192 + p * 8) = *(short8*)lo8;
  }
}

// ---------------- rmsq: inv_rms for the 32 q rows ----------------
__global__ __launch_bounds__(256) void rmsq_kernel(const float* __restrict__ hs,
                                                   const int* __restrict__ q_idx,
                                                   float* __restrict__ irq) {
  int qi = blockIdx.x, l = blockIdx.y, t = threadIdx.x;
  int s = q_idx[qi];
  const float* row = hs + ((size_t)l * SEQ + s) * DIM;
  float4 v0 = *(const float4*)(row + t * 4);
  float4 v1 = *(const float4*)(row + t * 4 + 1024);
  float acc = v0.x*v0.x + v0.y*v0.y + v0.z*v0.z + v0.w*v0.w
            + v1.x*v1.x + v1.y*v1.y + v1.z*v1.z + v1.w*v1.w;
  #pragma unroll
  for (int off = 32; off >= 1; off >>= 1) acc += __shfl_down(acc, off);
  __shared__ float red[4];
  if ((t & 63) == 0) red[t >> 6] = acc;
  __syncthreads();
  if (t == 0) {
    float tot = red[0] + red[1] + red[2] + red[3];
    irq[l * NQ + qi] = rsqrtf(tot / (float)DIM + 1e-6f);
  }
}

// ---------------- cossin: mrope tables [S][HD] ----------------
__global__ void cossin_kernel(const int* __restrict__ pos_ids,
                              float* __restrict__ cost, float* __restrict__ sint) {
  int idx = blockIdx.x * 256 + threadIdx.x;
  int s = idx >> 7, d = idx & 127;
  int t = (d < 32) ? 0 : (d < 80 ? 1 : 2);
  int j = d & 63;
  double invf = pow(1000000.0, -(double)j / 64.0);
  double ph = (double)pos_ids[t * SEQ + s] * invf;
  cost[idx] = (float)cos(ph);
  sint[idx] = (float)sin(ph);
}

// ---------------- xqt: xqT[l][k][32] = hs[qrow]*ir*ln_w, k-major ----------------
__global__ __launch_bounds__(256) void xqt_kernel(
    const float* __restrict__ hs, const float* __restrict__ ln_w,
    const int* __restrict__ q_idx, const float* __restrict__ irq,
    float* __restrict__ xqT) {
  __shared__ float tile[32][132];
  __shared__ int qix[32];
  __shared__ float qir[32];
  int kc = blockIdx.x, l = blockIdx.y, t = threadIdx.x;
  if (t < 32) { qix[t] = q_idx[t]; qir[t] = irq[l * NQ + t]; }
  __syncthreads();
  int q = t >> 3, sub = t & 7;
  const float* src = hs + ((size_t)l * SEQ + qix[q]) * DIM + kc * 128 + sub * 16;
  const float* lnp = ln_w + l * DIM + kc * 128 + sub * 16;
  float ir = qir[q];
  #pragma unroll
  for (int e = 0; e < 16; e += 4) {
    float4 v = *(const float4*)(src + e);
    float4 w = *(const float4*)(lnp + e);
    tile[q][sub * 16 + e + 0] = v.x * ir * w.x;
    tile[q][sub * 16 + e + 1] = v.y * ir * w.y;
    tile[q][sub * 16 + e + 2] = v.z * ir * w.z;
    tile[q][sub * 16 + e + 3] = v.w * ir * w.w;
  }
  __syncthreads();
  float* dst = xqT + ((size_t)l * DIM + kc * 128) * 32;
  #pragma unroll
  for (int i = 0; i < 4; ++i) {
    int flat = t * 4 + i * 1024;
    int kk = flat >> 5, qq = flat & 31;
    float4 o;
    o.x = tile[qq + 0][kk];
    o.y = tile[qq + 1][kk];
    o.z = tile[qq + 2][kk];
    o.w = tile[qq + 3][kk];
    *(float4*)(dst + flat) = o;
  }
}

// ---------------- kgemm: K proj, bf16x3 MFMA, fused RMSNorm + bias + RoPE ----------------
// BM=128 BN=256 BK=32, 512 thr = 8 waves (2m x 4n), frag-lane-linear LDS, 2-phase dbuf
__global__ __launch_bounds__(512) void kgemm_kernel(
    const float* __restrict__ hs, const short* __restrict__ W2,
    const float* __restrict__ k_b, const float* __restrict__ cost,
    const float* __restrict__ sint, float* __restrict__ Kbuf) {
  __shared__ short As[2][2][8][512];    // [buf][half][mfrag][lane*8] 32KB
  __shared__ short Bs[2][2][16][512];   // [buf][half][nfrag][lane*8] 64KB
  __shared__ float sqred[128][4];
  __shared__ float irs[128];

  int t = threadIdx.x;
  int s0 = blockIdx.x * 128;
  int l = blockIdx.y;
  int lane = t & 63, w = t >> 6;
  int wm = w >> 2, wn = w & 3;
  int fr = lane & 15, kg = lane >> 4;

  int arow = t >> 2;            // 0..127 staging row
  int akg = t & 3;              // staging k-subgroup
  const float* hrow = hs + ((size_t)l * SEQ + s0 + arow) * DIM + akg * 8;
  const short* wbase = W2 + (size_t)l * 64 * 16384;

  f32x4 acc[4][4];
  #pragma unroll
  for (int mf = 0; mf < 4; ++mf)
    #pragma unroll
    for (int nf = 0; nf < 4; ++nf) acc[mf][nf] = (f32x4){0.f, 0.f, 0.f, 0.f};
  float sq = 0.f;
  int amf = arow >> 4;
  int aslot = akg * 16 + (arow & 15);

  // prologue: stage kb=0 into buf 0
  {
    const char* src = (const char*)wbase;
    char* dst = (char*)&Bs[0][0][0][0];
    #pragma unroll
    for (int c = 0; c < 4; ++c) {
      int off = (w * 4 + c) * 1024;
      GLOAD16(src + off + lane * 16, dst + off);
    }
    float4 a0 = *(const float4*)(hrow);
    float4 a1 = *(const float4*)(hrow + 4);
    float av[8] = {a0.x, a0.y, a0.z, a0.w, a1.x, a1.y, a1.z, a1.w};
    short hi8[8], lo8[8];
    #pragma unroll
    for (int e = 0; e < 8; ++e) {
      sq += av[e] * av[e];
      short h = f2bf(av[e]);
      hi8[e] = h;
      lo8[e] = f2bf(av[e] - bf2f(h));
    }
    *(short8*)(&As[0][0][amf][aslot * 8]) = *(short8*)hi8;
    *(short8*)(&As[0][1][amf][aslot * 8]) = *(short8*)lo8;
  }
  __syncthreads();

  for (int kb = 0; kb < 64; ++kb) {
    int buf = kb & 1;
    int nxt = kb + 1;
    float4 a0, a1;
    if (nxt < 64) {
      const char* src = (const char*)(wbase + (size_t)nxt * 16384);
      char* dst = (char*)&Bs[nxt & 1][0][0][0];
      #pragma unroll
      for (int c = 0; c < 4; ++c) {
        int off = (w * 4 + c) * 1024;
        GLOAD16(src + off + lane * 16, dst + off);
      }
      a0 = *(const float4*)(hrow + nxt * 32);
      a1 = *(const float4*)(hrow + nxt * 32 + 4);
    }
    // compute tile kb
    short8 ah[4], al[4];
    #pragma unroll
    for (int mf = 0; mf < 4; ++mf) {
      ah[mf] = *(const short8*)(&As[buf][0][wm * 4 + mf][lane * 8]);
      al[mf] = *(const short8*)(&As[buf][1][wm * 4 + mf][lane * 8]);
    }
    #pragma unroll
    for (int nf = 0; nf < 4; ++nf) {
      int fi = wn + nf * 4;
      short8 bh = *(const short8*)(&Bs[buf][0][fi][lane * 8]);
      short8 bl = *(const short8*)(&Bs[buf][1][fi][lane * 8]);
      #pragma unroll
      for (int mf = 0; mf < 4; ++mf) {
        acc[mf][nf] = __builtin_amdgcn_mfma_f32_16x16x32_bf16(ah[mf], bh, acc[mf][nf], 0, 0, 0);
        acc[mf][nf] = __builtin_amdgcn_mfma_f32_16x16x32_bf16(ah[mf], bl, acc[mf][nf], 0, 0, 0);
        acc[mf][nf] = __builtin_amdgcn_mfma_f32_16x16x32_bf16(al[mf], bh, acc[mf][nf], 0, 0, 0);
      }
    }
    if (nxt < 64) {
      float av[8] = {a0.x, a0.y, a0.z, a0.w, a1.x, a1.y, a1.z, a1.w};
      short hi8[8], lo8[8];
      #pragma unroll
      for (int e = 0; e < 8; ++e) {
        sq += av[e] * av[e];
        short h = f2bf(av[e]);
        hi8[e] = h;
        lo8[e] = f2bf(av[e] - bf2f(h));
      }
      *(short8*)(&As[nxt & 1][0][amf][aslot * 8]) = *(short8*)hi8;
      *(short8*)(&As[nxt & 1][1][amf][aslot * 8]) = *(short8*)lo8;
    }
    __syncthreads();
  }

  // inv_rms
  sqred[arow][akg] = sq;
  __syncthreads();
  if (t < 128) {
    float tot = sqred[t][0] + sqred[t][1] + sqred[t][2] + sqred[t][3];
    irs[t] = rsqrtf(tot / (float)DIM + 1e-6f);
  }
  __syncthreads();

  // epilogue: ir scale + bias + rope, store fp32 roped K
  int j = wn * 16 + fr;  // 0..63 within head
  float b_h0l = k_b[l * NKV + j];
  float b_h0h = k_b[l * NKV + j + 64];
  float b_h1l = k_b[l * NKV + 128 + j];
  float b_h1h = k_b[l * NKV + 128 + j + 64];
  #pragma unroll
  for (int mf = 0; mf < 4; ++mf) {
    #pragma unroll
    for (int r = 0; r < 4; ++r) {
      int row = wm * 64 + mf * 16 + kg * 4 + r;
      int s = s0 + row;
      float ir = irs[row];
      float cj = cost[s * HD + j], sj = sint[s * HD + j];
      float cj2 = cost[s * HD + j + 64], sj2 = sint[s * HD + j + 64];
      float k0l = acc[mf][0][r] * ir + b_h0l;
      float k0h = acc[mf][1][r] * ir + b_h0h;
      float k1l = acc[mf][2][r] * ir + b_h1l;
      float k1h = acc[mf][3][r] * ir + b_h1h;
      float* orow = Kbuf + ((size_t)l * SEQ + s) * NKV;
      orow[j]          = k0l * cj - k0h * sj;
      orow[j + 64]     = k0h * cj2 + k0l * sj2;
      orow[128 + j]    = k1l * cj - k1h * sj;
      orow[128 + j+64] = k1h * cj2 + k1l * sj2;
    }
  }
}

// ---------------- kpack: roped fp32 K -> frag-lane-linear bf16 hi/lo blob ----------------
// blob per (l,kv,kc): 32768 shorts = [t=0..3][hi f0..7][lo f0..7], slot=(f<<6)|lane (512 shorts per f)
__global__ __launch_bounds__(256) void kpack_kernel(const float* __restrict__ Kbuf,
                                                    short* __restrict__ Kblob) {
  int kc = blockIdx.x, kv = blockIdx.y, l = blockIdx.z, t = threadIdx.x;
  short* blob = Kblob + (size_t)((l * 2 + kv) * 32 + kc) * 32768;
  #pragma unroll
  for (int i = 0; i < 8; ++i) {
    int p = t + i * 256;               // [ts4][f8][lane64]
    int ts = p >> 9, f = (p >> 6) & 7, lane = p & 63;
    int key = kc * 128 + f * 16 + (lane & 15);
    int d0 = ts * 32 + (lane >> 4) * 8;
    const float* src = Kbuf + ((size_t)l * SEQ + key) * NKV + kv * HD + d0;
    float4 v0 = *(const float4*)src;
    float4 v1 = *(const float4*)(src + 4);
    float av[8] = {v0.x, v0.y, v0.z, v0.w, v1.x, v1.y, v1.z, v1.w};
    short hi8[8], lo8[8];
    #pragma unroll
    for (int e = 0; e < 8; ++e) {
      short h = f2bf(av[e]);
      hi8[e] = h;
      lo8[e] = f2bf(av[e] - bf2f(h));
    }
    *(short8*)(blob + ((ts * 2 + 0) * 8 + f) * 512 + lane * 8) = *(short8*)hi8;
    *(short8*)(blob + ((ts * 2 + 1) * 8 + f) * 512 + lane * 8) = *(short8*)lo8;
  }
}

// ---------------- qgemm: Q = xq . q_w, fp32, k split 8-way, full grid ----------------
__global__ __launch_bounds__(512) void qgemm_kernel(
    const float* __restrict__ q_w, const float* __restrict__ q_b,
    const float* __restrict__ xqT, float* __restrict__ Qbuf) {
  __shared__ float part[8][32][64];   // 64KB
  int t = threadIdx.x;
  int nc = blockIdx.x, l = blockIdx.y;
  int c = t & 63, sl = t >> 6;
  const float* wp = q_w + (size_t)l * DIM * NQE + nc * 64 + c;
  const float* xp = xqT + (size_t)l * DIM * 32;
  float acc[32];
  #pragma unroll
  for (int r = 0; r < 32; ++r) acc[r] = 0.f;
  int k0 = sl * 256;
  for (int k4 = 0; k4 < 64; ++k4) {
    int k = k0 + k4 * 4;
    float w0 = wp[(size_t)(k + 0) * NQE];
    float w1 = wp[(size_t)(k + 1) * NQE];
    float w2 = wp[(size_t)(k + 2) * NQE];
    float w3 = wp[(size_t)(k + 3) * NQE];
    const float* x0 = xp + (size_t)(k + 0) * 32;
    const float* x1 = xp + (size_t)(k + 1) * 32;
    const float* x2 = xp + (size_t)(k + 2) * 32;
    const float* x3 = xp + (size_t)(k + 3) * 32;
    #pragma unroll
    for (int r = 0; r < 32; ++r) {
      float a = fmaf(w0, x0[r], fmaf(w1, x1[r], fmaf(w2, x2[r], fmaf(w3, x3[r], acc[r]))));
      acc[r] = a;
    }
  }
  #pragma unroll
  for (int r = 0; r < 32; ++r) part[sl][r][c] = acc[r];
  __syncthreads();
  #pragma unroll
  for (int i = 0; i < 4; ++i) {
    int p = t + i * 512;
    int r = p >> 6, cc = p & 63;
    float v = part[0][r][cc] + part[1][r][cc] + part[2][r][cc] + part[3][r][cc]
            + part[4][r][cc] + part[5][r][cc] + part[6][r][cc] + part[7][r][cc]
            + q_b[l * NQE + nc * 64 + cc];
    Qbuf[((size_t)l * NQ + r) * NQE + nc * 64 + cc] = v;
  }
}

// ---------------- qpack: rope Q + split to frag-lane-linear blob ----------------
// blob per (l,kv): 65536 shorts = [t4][hi f0..15][lo f0..15], 512 shorts per f
__global__ __launch_bounds__(256) void qpack_kernel(
    const float* __restrict__ Qbuf, const float* __restrict__ cost,
    const float* __restrict__ sint, const int* __restrict__ q_idx,
    short* __restrict__ Qblob) {
  int kv = blockIdx.x, l = blockIdx.y, t = threadIdx.x;
  short* blob = Qblob + (size_t)(l * 2 + kv) * 65536;
  #pragma unroll
  for (int i = 0; i < 16; ++i) {
    int p = t + i * 256;               // [ts4][f16][lane64]
    int ts = p >> 10, f = (p >> 6) & 15, lane = p & 63;
    int row = f * 16 + (lane & 15);
    int hh = row >> 5, q = row & 31;
    int h = kv * 8 + hh;
    int d0 = ts * 32 + (lane >> 4) * 8;
    int s = q_idx[q];
    const float* qrow = Qbuf + ((size_t)l * NQ + q) * NQE + h * HD;
    const float* ct = cost + s * HD;
    const float* st = sint + s * HD;
    short hi8[8], lo8[8];
    #pragma unroll
    for (int e = 0; e < 8; ++e) {
      int d = d0 + e;
      float x = qrow[d];
      float xp = qrow[d ^ 64];
      float v = (d < 64) ? (x * ct[d] - xp * st[d]) : (x * ct[d] + xp * st[d]);
      short h2 = f2bf(v);
      hi8[e] = h2;
      lo8[e] = f2bf(v - bf2f(h2));
    }
    *(short8*)(blob + ((ts * 2 + 0) * 16 + f) * 512 + lane * 8) = *(short8*)hi8;
    *(short8*)(blob + ((ts * 2 + 1) * 16 + f) * 512 + lane * 8) = *(short8*)lo8;
  }
}

// ---------------- scores: bf16x3 MFMA, M=256 (8 heads x 32 q) x 128 keys ----------------
__global__ __launch_bounds__(512) void scores_kernel(
    const short* __restrict__ Qblob, const short* __restrict__ Kblob,
    const int* __restrict__ q_idx, float* __restrict__ out) {
  __shared__ short Qs[2][16384];   // per t-step 32KB, x2 buf
  __shared__ short Ks[2][8192];    // per t-step 16KB, x2 buf
  __shared__ int qiv[32];
  int t = threadIdx.x;
  int kc = blockIdx.x, kv = blockIdx.y, l = blockIdx.z;
  int lane = t & 63, w = t >> 6;
  int wm = w >> 1, wn = w & 1;
  if (t < 32) qiv[t] = q_idx[t];
  const char* qsrc = (const char*)(Qblob + (size_t)(l * 2 + kv) * 65536);
  const char* ksrc = (const char*)(Kblob + (size_t)((l * 2 + kv) * 32 + kc) * 32768);
  // prologue stage ts=0
  #pragma unroll
  for (int c = 0; c < 4; ++c) {
    int off = (w * 4 + c) * 1024;
    GLOAD16(qsrc + off + lane * 16, (char*)Qs[0] + off);
  }
  #pragma unroll
  for (int c = 0; c < 2; ++c) {
    int off = (w * 2 + c) * 1024;
    GLOAD16(ksrc + off + lane * 16, (char*)Ks[0] + off);
  }
  f32x4 acc[4][4];
  #pragma unroll
  for (int mf = 0; mf < 4; ++mf)
    #pragma unroll
    for (int nf = 0; nf < 4; ++nf) acc[mf][nf] = (f32x4){0.f, 0.f, 0.f, 0.f};
  __syncthreads();
  for (int ts = 0; ts < 4; ++ts) {
    int buf = ts & 1;
    if (ts < 3) {
      const char* qs = qsrc + (ts + 1) * 32768;
      const char* ks = ksrc + (ts + 1) * 16384;
      #pragma unroll
      for (int c = 0; c < 4; ++c) {
        int off = (w * 4 + c) * 1024;
        GLOAD16(qs + off + lane * 16, (char*)Qs[(ts + 1) & 1] + off);
      }
      #pragma unroll
      for (int c = 0; c < 2; ++c) {
        int off = (w * 2 + c) * 1024;
        GLOAD16(ks + off + lane * 16, (char*)Ks[(ts + 1) & 1] + off);
      }
    }
    short8 ah[4], al[4];
    #pragma unroll
    for (int mf = 0; mf < 4; ++mf) {
      int f = wm * 4 + mf;
      ah[mf] = *(const short8*)(Qs[buf] + f * 512 + lane * 8);
      al[mf] = *(const short8*)(Qs[buf] + 8192 + f * 512 + lane * 8);
    }
    #pragma unroll
    for (int nf = 0; nf < 4; ++nf) {
      int f = wn * 4 + nf;
      short8 bh = *(const short8*)(Ks[buf] + f * 512 + lane * 8);
      short8 bl = *(const short8*)(Ks[buf] + 4096 + f * 512 + lane * 8);
      #pragma unroll
      for (int mf = 0; mf < 4; ++mf) {
        acc[mf][nf] = __builtin_amdgcn_mfma_f32_16x16x32_bf16(ah[mf], bh, acc[mf][nf], 0, 0, 0);
        acc[mf][nf] = __builtin_amdgcn_mfma_f32_16x16x32_bf16(ah[mf], bl, acc[mf][nf], 0, 0, 0);
        acc[mf][nf] = __builtin_amdgcn_mfma_f32_16x16x32_bf16(al[mf], bh, acc[mf][nf], 0, 0, 0);
      }
    }
    __syncthreads();
  }
  const float scale = 0.088388347648318447f;
  #pragma unroll
  for (int mf = 0; mf < 4; ++mf) {
    #pragma unroll
    for (int r = 0; r < 4; ++r) {
      int rr = wm * 64 + mf * 16 + (lane >> 4) * 4 + r;
      int hh = rr >> 5, q = rr & 31;
      int qv = qiv[q];
      float* orow = out + (((size_t)(l * NH + kv * 8 + hh)) * NQ + q) * SEQ;
      #pragma unroll
      for (int nf = 0; nf < 4; ++nf) {
        int key = kc * 128 + (wn * 4 + nf) * 16 + (lane & 15);
        orow[key] = (key > qv) ? -1e9f : acc[mf][nf][r] * scale;
      }
    }
  }
}

// ---------------- softmax over S ----------------
__global__ __launch_bounds__(256) void softmax_kernel(float* __restrict__ out) {
  size_t row = blockIdx.x;
  float* p = out + row * SEQ;
  int t = threadIdx.x;
  float4 v[4];
  float mx = -1e30f;
  #pragma unroll
  for (int i = 0; i < 4; ++i) {
    v[i] = *(const float4*)(p + t * 4 + i * 1024);
    mx = fmaxf(mx, fmaxf(fmaxf(v[i].x, v[i].y), fmaxf(v[i].z, v[i].w)));
  }
  #pragma unroll
  for (int off = 32; off >= 1; off >>= 1) mx = fmaxf(mx, __shfl_xor(mx, off));
  __shared__ float red[4];
  if ((t & 63) == 0) red[t >> 6] = mx;
  __syncthreads();
  mx = fmaxf(fmaxf(red[0], red[1]), fmaxf(red[2], red[3]));
  __syncthreads();
  float sum = 0.f;
  #pragma unroll
  for (int i = 0; i < 4; ++i) {
    v[i].x = __expf(v[i].x - mx); v[i].y = __expf(v[i].y - mx);
    v[i].z = __expf(v[i].z - mx); v[i].w = __expf(v[i].w - mx);
    sum += v[i].x + v[i].y + v[i].z + v[i].w;
  }
  #pragma unroll
  for (int off = 32; off >= 1; off >>= 1) sum += __shfl_xor(sum, off);
  if ((t & 63) == 0) red[t >> 6] = sum;
  __syncthreads();
  sum = red[0] + red[1] + red[2] + red[3];
  float inv = 1.f / sum;
  #pragma unroll
  for (int i = 0; i < 4; ++i) {
    v[i].x *= inv; v[i].y *= inv; v[i].z *= inv; v[i].w *= inv;
    *(float4*)(p + t * 4 + i * 1024) = v[i];
  }
}

extern "C" void kernel_launch(void* const* d_in, const int* in_sizes, int n_in,
                              void* d_out, int out_size, void* d_ws, size_t ws_size,
                              hipStream_t stream) {
  const float* hs   = (const float*)d_in[0];
  const float* ln_w = (const float*)d_in[1];
  const float* q_w  = (const float*)d_in[2];
  const float* q_b  = (const float*)d_in[3];
  const float* k_w  = (const float*)d_in[4];
  const float* k_b  = (const float*)d_in[5];
  const int* pos    = (const int*)d_in[6];
  const int* qidx   = (const int*)d_in[7];
  float* out = (float*)d_out;
  float* ws = (float*)d_ws;
  float* irq   = ws + WS_IRQ;
  float* xqT   = ws + WS_XQT;
  float* cost  = ws + WS_COS;
  float* sint  = ws + WS_SIN;
  float* Qbuf  = ws + WS_QBUF;
  float* Kbuf  = ws + WS_KBUF;
  short* W2    = (short*)(ws + WS_BIG);   // 16MB blob
  short* Kblob = (short*)(ws + WS_BIG);   // 32MB, overwrites W2 after kgemm
  short* Qblob = (short*)(ws + WS_QBLOB);

  prep_kernel<<<dim3(64, LYR), 256, 0, stream>>>(ln_w, k_w, W2);
  rmsq_kernel<<<dim3(NQ, LYR), 256, 0, stream>>>(hs, qidx, irq);
  cossin_kernel<<<(SEQ * HD) / 256, 256, 0, stream>>>(pos, cost, sint);
  xqt_kernel<<<dim3(16, LYR), 256, 0, stream>>>(hs, ln_w, qidx, irq, xqT);
  kgemm_kernel<<<dim3(SEQ / 128, LYR), 512, 0, stream>>>(hs, W2, k_b, cost, sint, Kbuf);
  kpack_kernel<<<dim3(32, 2, LYR), 256, 0, stream>>>(Kbuf, Kblob);
  qgemm_kernel<<<dim3(32, LYR), 512, 0, stream>>>(q_w, q_b, xqT, Qbuf);
  qpack_kernel<<<dim3(2, LYR), 256, 0, stream>>>(Qbuf, cost, sint, qidx, Qblob);
  scores_kernel<<<dim3(32, 2, LYR), 512, 0, stream>>>(Qblob, Kblob, qidx, out);
  softmax_kernel<<<LYR * NH * NQ, 256, 0, stream>>>(out);
}

// Round 4
// 374.425 us; speedup vs baseline: 1.9870x; 1.0772x over previous
//
#include <hip/hip_runtime.h>
#include <hip/hip_bf16.h>
#include <math.h>

#define LYR 8
#define SEQ 4096
#define DIM 2048
#define NH 16
#define HD 128
#define NQ 32
#define NKV 256   // KVH*HD
#define NQE 2048  // H*HD

typedef __attribute__((ext_vector_type(8))) short short8;
typedef __attribute__((ext_vector_type(4))) float f32x4;

// workspace layout (float units)
#define WS_IRQ   0                        // 256
#define WS_XQT   256                      // 524288
#define WS_COS   524544                   // 524288
#define WS_SIN   1048832                  // 524288
#define WS_QBUF  1573120                  // 524288
#define WS_W2    2097408                  // 4194304 floats = 8388608 shorts (16MB)
#define WS_KBLOB 6291712                  // 8388608 floats = 16777216 shorts (32MB)
#define WS_QBLOB 14680320                 // 524288 floats = 1048576 shorts
// end 15204608 floats ~ 60.8 MB

__device__ __forceinline__ short f2bf(float x) {
  __hip_bfloat16 h = __float2bfloat16(x);
  return *(short*)&h;
}
__device__ __forceinline__ float bf2f(short s) {
  unsigned u = ((unsigned)(unsigned short)s) << 16;
  return __uint_as_float(u);
}

#define GLOAD16(srcp, dstp) \
  __builtin_amdgcn_global_load_lds( \
      (const __attribute__((address_space(1))) unsigned int*)(srcp), \
      (__attribute__((address_space(3))) unsigned int*)(dstp), 16, 0, 0)

// ---------------- prep: W' = ln_w*k_w -> frag-lane-linear bf16 hi/lo blob ----------------
// blob per (l,kb): 16384 shorts = [hi: pos 0..1023][lo: pos 0..1023], pos=(f<<6)|lane
// content: W'[k = kb*32 + (lane>>4)*8 + e][n = f*16 + (lane&15)]
__global__ __launch_bounds__(256) void prep_kernel(
    const float* __restrict__ ln_w, const float* __restrict__ k_w,
    short* __restrict__ W2) {
  int kb = blockIdx.x, l = blockIdx.y, t = threadIdx.x;
  const float* kwl = k_w + (size_t)l * DIM * NKV;
  const float* lnl = ln_w + l * DIM;
  short* blob = W2 + (size_t)(l * 64 + kb) * 16384;
  #pragma unroll
  for (int i = 0; i < 4; ++i) {
    int p = t + i * 256;
    int fi = p >> 6, lane = p & 63;
    int n = fi * 16 + (lane & 15);
    int k0 = kb * 32 + (lane >> 4) * 8;
    short hi8[8], lo8[8];
    #pragma unroll
    for (int e = 0; e < 8; ++e) {
      float v = lnl[k0 + e] * kwl[(size_t)(k0 + e) * NKV + n];
      short h = f2bf(v);
      hi8[e] = h;
      lo8[e] = f2bf(v - bf2f(h));
    }
    *(short8*)(blob + p * 8) = *(short8*)hi8;
    *(short8*)(blob + 8192 + p * 8) = *(short8*)lo8;
  }
}

// ---------------- rmsq: inv_rms for the 32 q rows ----------------
__global__ __launch_bounds__(256) void rmsq_kernel(const float* __restrict__ hs,
                                                   const int* __restrict__ q_idx,
                                                   float* __restrict__ irq) {
  int qi = blockIdx.x, l = blockIdx.y, t = threadIdx.x;
  int s = q_idx[qi];
  const float* row = hs + ((size_t)l * SEQ + s) * DIM;
  float4 v0 = *(const float4*)(row + t * 4);
  float4 v1 = *(const float4*)(row + t * 4 + 1024);
  float acc = v0.x*v0.x + v0.y*v0.y + v0.z*v0.z + v0.w*v0.w
            + v1.x*v1.x + v1.y*v1.y + v1.z*v1.z + v1.w*v1.w;
  #pragma unroll
  for (int off = 32; off >= 1; off >>= 1) acc += __shfl_down(acc, off);
  __shared__ float red[4];
  if ((t & 63) == 0) red[t >> 6] = acc;
  __syncthreads();
  if (t == 0) {
    float tot = red[0] + red[1] + red[2] + red[3];
    irq[l * NQ + qi] = rsqrtf(tot / (float)DIM + 1e-6f);
  }
}

// ---------------- cossin: mrope tables [S][HD] ----------------
__global__ void cossin_kernel(const int* __restrict__ pos_ids,
                              float* __restrict__ cost, float* __restrict__ sint) {
  int idx = blockIdx.x * 256 + threadIdx.x;
  int s = idx >> 7, d = idx & 127;
  int t = (d < 32) ? 0 : (d < 80 ? 1 : 2);
  int j = d & 63;
  double invf = pow(1000000.0, -(double)j / 64.0);
  double ph = (double)pos_ids[t * SEQ + s] * invf;
  cost[idx] = (float)cos(ph);
  sint[idx] = (float)sin(ph);
}

// ---------------- xqt: xqT[l][k][32] = hs[qrow]*ir*ln_w, k-major ----------------
__global__ __launch_bounds__(256) void xqt_kernel(
    const float* __restrict__ hs, const float* __restrict__ ln_w,
    const int* __restrict__ q_idx, const float* __restrict__ irq,
    float* __restrict__ xqT) {
  __shared__ float tile[32][132];
  __shared__ int qix[32];
  __shared__ float qir[32];
  int kc = blockIdx.x, l = blockIdx.y, t = threadIdx.x;
  if (t < 32) { qix[t] = q_idx[t]; qir[t] = irq[l * NQ + t]; }
  __syncthreads();
  int q = t >> 3, sub = t & 7;
  const float* src = hs + ((size_t)l * SEQ + qix[q]) * DIM + kc * 128 + sub * 16;
  const float* lnp = ln_w + l * DIM + kc * 128 + sub * 16;
  float ir = qir[q];
  #pragma unroll
  for (int e = 0; e < 16; e += 4) {
    float4 v = *(const float4*)(src + e);
    float4 w = *(const float4*)(lnp + e);
    tile[q][sub * 16 + e + 0] = v.x * ir * w.x;
    tile[q][sub * 16 + e + 1] = v.y * ir * w.y;
    tile[q][sub * 16 + e + 2] = v.z * ir * w.z;
    tile[q][sub * 16 + e + 3] = v.w * ir * w.w;
  }
  __syncthreads();
  float* dst = xqT + ((size_t)l * DIM + kc * 128) * 32;
  #pragma unroll
  for (int i = 0; i < 4; ++i) {
    int flat = t * 4 + i * 1024;
    int kk = flat >> 5, qq = flat & 31;
    float4 o;
    o.x = tile[qq + 0][kk];
    o.y = tile[qq + 1][kk];
    o.z = tile[qq + 2][kk];
    o.w = tile[qq + 3][kk];
    *(float4*)(dst + flat) = o;
  }
}

// ---------------- kgemm: K proj bf16x3 MFMA + RMSNorm + bias + RoPE + blob write ----------------
// BM=64 BN=256 BK=32, 256 thr = 4 waves (1m x 4n), LDS exactly 80KB -> 2 blocks/CU
// flat grid 512: l = fid&7 (XCD-per-layer swizzle), sb = fid>>3
__global__ __launch_bounds__(256) void kgemm_kernel(
    const float* __restrict__ hs, const short* __restrict__ W2,
    const float* __restrict__ k_b, const float* __restrict__ cost,
    const float* __restrict__ sint, short* __restrict__ Kblob) {
  __shared__ __align__(1024) char SM[81920];  // As 16KB | Bs 64KB ; reused as Kraw+irs

  int t = threadIdx.x;
  int fid = blockIdx.x;
  int l = fid & 7, sb = fid >> 3;
  int s0 = sb * 64;
  int lane = t & 63, w = t >> 6;          // w = wn (0..3)
  int fr = lane & 15, kg = lane >> 4;
  int arow = t >> 2, akg = t & 3;

  const float* hrow = hs + ((size_t)l * SEQ + s0 + arow) * DIM + akg * 8;
  const char* wbase = (const char*)(W2 + (size_t)l * 64 * 16384);

  // As: [buf(8192B)][half(4096B)][mf(1024B)][swizzled lane slots]
  int amf = arow >> 4;
  int awoff = amf * 1024 + (((akg * 16 + (arow & 15)) * 16) ^ (akg << 5));
  int aroff = (lane * 16) ^ ((lane >> 4) << 5);

  f32x4 acc[4][4];
  #pragma unroll
  for (int mf = 0; mf < 4; ++mf)
    #pragma unroll
    for (int nf = 0; nf < 4; ++nf) acc[mf][nf] = (f32x4){0.f, 0.f, 0.f, 0.f};
  float sq = 0.f;

  // prologue: stage kb=0 into buf 0
  {
    #pragma unroll
    for (int c = 0; c < 8; ++c) {
      int chunk = w * 8 + c;
      GLOAD16(wbase + chunk * 1024 + lane * 16, SM + 16384 + chunk * 1024);
    }
    float4 a0 = *(const float4*)(hrow);
    float4 a1 = *(const float4*)(hrow + 4);
    float av[8] = {a0.x, a0.y, a0.z, a0.w, a1.x, a1.y, a1.z, a1.w};
    short hi8[8], lo8[8];
    #pragma unroll
    for (int e = 0; e < 8; ++e) {
      sq += av[e] * av[e];
      short h = f2bf(av[e]);
      hi8[e] = h;
      lo8[e] = f2bf(av[e] - bf2f(h));
    }
    *(short8*)(SM + awoff) = *(short8*)hi8;
    *(short8*)(SM + 4096 + awoff) = *(short8*)lo8;
  }
  __syncthreads();

  for (int kb = 0; kb < 64; ++kb) {
    int buf = kb & 1;
    char* asb = SM + buf * 8192;
    char* bsb = SM + 16384 + buf * 32768;
    float4 a0, a1;
    if (kb < 63) {
      const char* src = wbase + (size_t)(kb + 1) * 32768;
      char* dst = SM + 16384 + (buf ^ 1) * 32768;
      #pragma unroll
      for (int c = 0; c < 8; ++c) {
        int chunk = w * 8 + c;
        GLOAD16(src + chunk * 1024 + lane * 16, dst + chunk * 1024);
      }
      a0 = *(const float4*)(hrow + (kb + 1) * 32);
      a1 = *(const float4*)(hrow + (kb + 1) * 32 + 4);
    }
    // compute tile kb
    short8 ah[4], al[4];
    #pragma unroll
    for (int mf = 0; mf < 4; ++mf) {
      ah[mf] = *(const short8*)(asb + mf * 1024 + aroff);
      al[mf] = *(const short8*)(asb + 4096 + mf * 1024 + aroff);
    }
    #pragma unroll
    for (int nf = 0; nf < 4; ++nf) {
      int f = w + nf * 4;
      short8 bh = *(const short8*)(bsb + f * 1024 + lane * 16);
      short8 bl = *(const short8*)(bsb + 16384 + f * 1024 + lane * 16);
      #pragma unroll
      for (int mf = 0; mf < 4; ++mf) {
        acc[mf][nf] = __builtin_amdgcn_mfma_f32_16x16x32_bf16(ah[mf], bh, acc[mf][nf], 0, 0, 0);
        acc[mf][nf] = __builtin_amdgcn_mfma_f32_16x16x32_bf16(ah[mf], bl, acc[mf][nf], 0, 0, 0);
        acc[mf][nf] = __builtin_amdgcn_mfma_f32_16x16x32_bf16(al[mf], bh, acc[mf][nf], 0, 0, 0);
      }
    }
    if (kb < 63) {
      char* asn = SM + (buf ^ 1) * 8192;
      float av[8] = {a0.x, a0.y, a0.z, a0.w, a1.x, a1.y, a1.z, a1.w};
      short hi8[8], lo8[8];
      #pragma unroll
      for (int e = 0; e < 8; ++e) {
        sq += av[e] * av[e];
        short h = f2bf(av[e]);
        hi8[e] = h;
        lo8[e] = f2bf(av[e] - bf2f(h));
      }
      *(short8*)(asn + awoff) = *(short8*)hi8;
      *(short8*)(asn + 4096 + awoff) = *(short8*)lo8;
    }
    __syncthreads();
  }

  // ---- epilogue ----
  // row sumsq: lanes (t, t^1, t^2) share arow
  sq += __shfl_xor(sq, 1);
  sq += __shfl_xor(sq, 2);
  float* irs = (float*)(SM + 66560);   // 64 floats, after Kraw region
  if ((t & 3) == 0) irs[arow] = rsqrtf(sq / (float)DIM + 1e-6f);
  __syncthreads();

  // pass1: ir*acc + bias, rope in regs, store fp32 to Kraw[64][260]
  float* Kraw = (float*)SM;
  int j = w * 16 + fr;                 // 0..63 (lo-half col within head)
  float bias0 = k_b[l * NKV + j];
  float bias1 = k_b[l * NKV + j + 64];
  float bias2 = k_b[l * NKV + j + 128];
  float bias3 = k_b[l * NKV + j + 192];
  #pragma unroll
  for (int mf = 0; mf < 4; ++mf) {
    #pragma unroll
    for (int r = 0; r < 4; ++r) {
      int row = mf * 16 + kg * 4 + r;
      int s = s0 + row;
      float ir = irs[row];
      float v0 = acc[mf][0][r] * ir + bias0;
      float v1 = acc[mf][1][r] * ir + bias1;
      float v2 = acc[mf][2][r] * ir + bias2;
      float v3 = acc[mf][3][r] * ir + bias3;
      float cj = cost[s * HD + j], sj = sint[s * HD + j];
      float cj2 = cost[s * HD + j + 64], sj2 = sint[s * HD + j + 64];
      float* kr = Kraw + row * 260;
      kr[j]       = v0 * cj - v1 * sj;
      kr[j + 64]  = v1 * cj2 + v0 * sj2;
      kr[j + 128] = v2 * cj - v3 * sj;
      kr[j + 192] = v3 * cj2 + v2 * sj2;
    }
  }
  __syncthreads();

  // pass2: split + write blob. chunks [kv2][ts4][fl4][lane64]
  int kc = sb >> 1, fb = (sb & 1) * 4;
  #pragma unroll
  for (int i = 0; i < 8; ++i) {
    int c = t + i * 256;
    int lc = c & 63, fl = (c >> 6) & 3, ts = (c >> 8) & 3, kv = c >> 10;
    int key = fl * 16 + (lc & 15);
    int d0 = kv * 128 + ts * 32 + (lc >> 4) * 8;
    float4 x0 = *(const float4*)(Kraw + key * 260 + d0);
    float4 x1 = *(const float4*)(Kraw + key * 260 + d0 + 4);
    float av[8] = {x0.x, x0.y, x0.z, x0.w, x1.x, x1.y, x1.z, x1.w};
    short hi8[8], lo8[8];
    #pragma unroll
    for (int e = 0; e < 8; ++e) {
      short h = f2bf(av[e]);
      hi8[e] = h;
      lo8[e] = f2bf(av[e] - bf2f(h));
    }
    short* bb = Kblob + (size_t)((l * 2 + kv) * 32 + kc) * 32768
              + (size_t)((ts * 2 + 0) * 8 + fb + fl) * 512 + lc * 8;
    *(short8*)bb = *(short8*)hi8;
    *(short8*)(bb + 4096) = *(short8*)lo8;
  }
}

// ---------------- qgemm: Q = xq . q_w, fp32, k split 8-way ----------------
__global__ __launch_bounds__(512) void qgemm_kernel(
    const float* __restrict__ q_w, const float* __restrict__ q_b,
    const float* __restrict__ xqT, float* __restrict__ Qbuf) {
  __shared__ float part[8][32][64];   // 64KB
  int t = threadIdx.x;
  int nc = blockIdx.x, l = blockIdx.y;
  int c = t & 63, sl = t >> 6;
  const float* wp = q_w + (size_t)l * DIM * NQE + nc * 64 + c;
  const float* xp = xqT + (size_t)l * DIM * 32;
  float acc[32];
  #pragma unroll
  for (int r = 0; r < 32; ++r) acc[r] = 0.f;
  int k0 = sl * 256;
  for (int k4 = 0; k4 < 64; ++k4) {
    int k = k0 + k4 * 4;
    float w0 = wp[(size_t)(k + 0) * NQE];
    float w1 = wp[(size_t)(k + 1) * NQE];
    float w2 = wp[(size_t)(k + 2) * NQE];
    float w3 = wp[(size_t)(k + 3) * NQE];
    const float* x0 = xp + (size_t)(k + 0) * 32;
    const float* x1 = xp + (size_t)(k + 1) * 32;
    const float* x2 = xp + (size_t)(k + 2) * 32;
    const float* x3 = xp + (size_t)(k + 3) * 32;
    #pragma unroll
    for (int r = 0; r < 32; ++r) {
      float a = fmaf(w0, x0[r], fmaf(w1, x1[r], fmaf(w2, x2[r], fmaf(w3, x3[r], acc[r]))));
      acc[r] = a;
    }
  }
  #pragma unroll
  for (int r = 0; r < 32; ++r) part[sl][r][c] = acc[r];
  __syncthreads();
  #pragma unroll
  for (int i = 0; i < 4; ++i) {
    int p = t + i * 512;
    int r = p >> 6, cc = p & 63;
    float v = part[0][r][cc] + part[1][r][cc] + part[2][r][cc] + part[3][r][cc]
            + part[4][r][cc] + part[5][r][cc] + part[6][r][cc] + part[7][r][cc]
            + q_b[l * NQE + nc * 64 + cc];
    Qbuf[((size_t)l * NQ + r) * NQE + nc * 64 + cc] = v;
  }
}

// ---------------- qpack: rope Q + split to frag-lane-linear blob ----------------
__global__ __launch_bounds__(256) void qpack_kernel(
    const float* __restrict__ Qbuf, const float* __restrict__ cost,
    const float* __restrict__ sint, const int* __restrict__ q_idx,
    short* __restrict__ Qblob) {
  int kv = blockIdx.x, l = blockIdx.y, t = threadIdx.x;
  short* blob = Qblob + (size_t)(l * 2 + kv) * 65536;
  #pragma unroll
  for (int i = 0; i < 16; ++i) {
    int p = t + i * 256;               // [ts4][f16][lane64]
    int ts = p >> 10, f = (p >> 6) & 15, lane = p & 63;
    int row = f * 16 + (lane & 15);
    int hh = row >> 5, q = row & 31;
    int h = kv * 8 + hh;
    int d0 = ts * 32 + (lane >> 4) * 8;
    int s = q_idx[q];
    const float* qrow = Qbuf + ((size_t)l * NQ + q) * NQE + h * HD;
    const float* ct = cost + s * HD;
    const float* st = sint + s * HD;
    short hi8[8], lo8[8];
    #pragma unroll
    for (int e = 0; e < 8; ++e) {
      int d = d0 + e;
      float x = qrow[d];
      float xp = qrow[d ^ 64];
      float v = (d < 64) ? (x * ct[d] - xp * st[d]) : (x * ct[d] + xp * st[d]);
      short h2 = f2bf(v);
      hi8[e] = h2;
      lo8[e] = f2bf(v - bf2f(h2));
    }
    *(short8*)(blob + ((ts * 2 + 0) * 16 + f) * 512 + lane * 8) = *(short8*)hi8;
    *(short8*)(blob + ((ts * 2 + 1) * 16 + f) * 512 + lane * 8) = *(short8*)lo8;
  }
}

// ---------------- scores: bf16x3 MFMA, M=256 (8 heads x 32 q) x 128 keys ----------------
__global__ __launch_bounds__(512) void scores_kernel(
    const short* __restrict__ Qblob, const short* __restrict__ Kblob,
    const int* __restrict__ q_idx, float* __restrict__ out) {
  __shared__ short Qs[2][16384];
  __shared__ short Ks[2][8192];
  __shared__ int qiv[32];
  int t = threadIdx.x;
  int kc = blockIdx.x, kv = blockIdx.y, l = blockIdx.z;
  int lane = t & 63, w = t >> 6;
  int wm = w >> 1, wn = w & 1;
  if (t < 32) qiv[t] = q_idx[t];
  const char* qsrc = (const char*)(Qblob + (size_t)(l * 2 + kv) * 65536);
  const char* ksrc = (const char*)(Kblob + (size_t)((l * 2 + kv) * 32 + kc) * 32768);
  #pragma unroll
  for (int c = 0; c < 4; ++c) {
    int off = (w * 4 + c) * 1024;
    GLOAD16(qsrc + off + lane * 16, (char*)Qs[0] + off);
  }
  #pragma unroll
  for (int c = 0; c < 2; ++c) {
    int off = (w * 2 + c) * 1024;
    GLOAD16(ksrc + off + lane * 16, (char*)Ks[0] + off);
  }
  f32x4 acc[4][4];
  #pragma unroll
  for (int mf = 0; mf < 4; ++mf)
    #pragma unroll
    for (int nf = 0; nf < 4; ++nf) acc[mf][nf] = (f32x4){0.f, 0.f, 0.f, 0.f};
  __syncthreads();
  for (int ts = 0; ts < 4; ++ts) {
    int buf = ts & 1;
    if (ts < 3) {
      const char* qs = qsrc + (ts + 1) * 32768;
      const char* ks = ksrc + (ts + 1) * 16384;
      #pragma unroll
      for (int c = 0; c < 4; ++c) {
        int off = (w * 4 + c) * 1024;
        GLOAD16(qs + off + lane * 16, (char*)Qs[(ts + 1) & 1] + off);
      }
      #pragma unroll
      for (int c = 0; c < 2; ++c) {
        int off = (w * 2 + c) * 1024;
        GLOAD16(ks + off + lane * 16, (char*)Ks[(ts + 1) & 1] + off);
      }
    }
    short8 ah[4], al[4];
    #pragma unroll
    for (int mf = 0; mf < 4; ++mf) {
      int f = wm * 4 + mf;
      ah[mf] = *(const short8*)(Qs[buf] + f * 512 + lane * 8);
      al[mf] = *(const short8*)(Qs[buf] + 8192 + f * 512 + lane * 8);
    }
    #pragma unroll
    for (int nf = 0; nf < 4; ++nf) {
      int f = wn * 4 + nf;
      short8 bh = *(const short8*)(Ks[buf] + f * 512 + lane * 8);
      short8 bl = *(const short8*)(Ks[buf] + 4096 + f * 512 + lane * 8);
      #pragma unroll
      for (int mf = 0; mf < 4; ++mf) {
        acc[mf][nf] = __builtin_amdgcn_mfma_f32_16x16x32_bf16(ah[mf], bh, acc[mf][nf], 0, 0, 0);
        acc[mf][nf] = __builtin_amdgcn_mfma_f32_16x16x32_bf16(ah[mf], bl, acc[mf][nf], 0, 0, 0);
        acc[mf][nf] = __builtin_amdgcn_mfma_f32_16x16x32_bf16(al[mf], bh, acc[mf][nf], 0, 0, 0);
      }
    }
    __syncthreads();
  }
  const float scale = 0.088388347648318447f;
  #pragma unroll
  for (int mf = 0; mf < 4; ++mf) {
    #pragma unroll
    for (int r = 0; r < 4; ++r) {
      int rr = wm * 64 + mf * 16 + (lane >> 4) * 4 + r;
      int hh = rr >> 5, q = rr & 31;
      int qv = qiv[q];
      float* orow = out + (((size_t)(l * NH + kv * 8 + hh)) * NQ + q) * SEQ;
      #pragma unroll
      for (int nf = 0; nf < 4; ++nf) {
        int key = kc * 128 + (wn * 4 + nf) * 16 + (lane & 15);
        orow[key] = (key > qv) ? -1e9f : acc[mf][nf][r] * scale;
      }
    }
  }
}

// ---------------- softmax over S ----------------
__global__ __launch_bounds__(256) void softmax_kernel(float* __restrict__ out) {
  size_t row = blockIdx.x;
  float* p = out + row * SEQ;
  int t = threadIdx.x;
  float4 v[4];
  float mx = -1e30f;
  #pragma unroll
  for (int i = 0; i < 4; ++i) {
    v[i] = *(const float4*)(p + t * 4 + i * 1024);
    mx = fmaxf(mx, fmaxf(fmaxf(v[i].x, v[i].y), fmaxf(v[i].z, v[i].w)));
  }
  #pragma unroll
  for (int off = 32; off >= 1; off >>= 1) mx = fmaxf(mx, __shfl_xor(mx, off));
  __shared__ float red[4];
  if ((t & 63) == 0) red[t >> 6] = mx;
  __syncthreads();
  mx = fmaxf(fmaxf(red[0], red[1]), fmaxf(red[2], red[3]));
  __syncthreads();
  float sum = 0.f;
  #pragma unroll
  for (int i = 0; i < 4; ++i) {
    v[i].x = __expf(v[i].x - mx); v[i].y = __expf(v[i].y - mx);
    v[i].z = __expf(v[i].z - mx); v[i].w = __expf(v[i].w - mx);
    sum += v[i].x + v[i].y + v[i].z + v[i].w;
  }
  #pragma unroll
  for (int off = 32; off >= 1; off >>= 1) sum += __shfl_xor(sum, off);
  if ((t & 63) == 0) red[t >> 6] = sum;
  __syncthreads();
  sum = red[0] + red[1] + red[2] + red[3];
  float inv = 1.f / sum;
  #pragma unroll
  for (int i = 0; i < 4; ++i) {
    v[i].x *= inv; v[i].y *= inv; v[i].z *= inv; v[i].w *= inv;
    *(float4*)(p + t * 4 + i * 1024) = v[i];
  }
}

extern "C" void kernel_launch(void* const* d_in, const int* in_sizes, int n_in,
                              void* d_out, int out_size, void* d_ws, size_t ws_size,
                              hipStream_t stream) {
  const float* hs   = (const float*)d_in[0];
  const float* ln_w = (const float*)d_in[1];
  const float* q_w  = (const float*)d_in[2];
  const float* q_b  = (const float*)d_in[3];
  const float* k_w  = (const float*)d_in[4];
  const float* k_b  = (const float*)d_in[5];
  const int* pos    = (const int*)d_in[6];
  const int* qidx   = (const int*)d_in[7];
  float* out = (float*)d_out;
  float* ws = (float*)d_ws;
  float* irq   = ws + WS_IRQ;
  float* xqT   = ws + WS_XQT;
  float* cost  = ws + WS_COS;
  float* sint  = ws + WS_SIN;
  float* Qbuf  = ws + WS_QBUF;
  short* W2    = (short*)(ws + WS_W2);
  short* Kblob = (short*)(ws + WS_KBLOB);
  short* Qblob = (short*)(ws + WS_QBLOB);

  prep_kernel<<<dim3(64, LYR), 256, 0, stream>>>(ln_w, k_w, W2);
  rmsq_kernel<<<dim3(NQ, LYR), 256, 0, stream>>>(hs, qidx, irq);
  cossin_kernel<<<(SEQ * HD) / 256, 256, 0, stream>>>(pos, cost, sint);
  xqt_kernel<<<dim3(16, LYR), 256, 0, stream>>>(hs, ln_w, qidx, irq, xqT);
  kgemm_kernel<<<512, 256, 0, stream>>>(hs, W2, k_b, cost, sint, Kblob);
  qgemm_kernel<<<dim3(32, LYR), 512, 0, stream>>>(q_w, q_b, xqT, Qbuf);
  qpack_kernel<<<dim3(2, LYR), 256, 0, stream>>>(Qbuf, cost, sint, qidx, Qblob);
  scores_kernel<<<dim3(32, 2, LYR), 512, 0, stream>>>(Qblob, Kblob, qidx, out);
  softmax_kernel<<<LYR * NH * NQ, 256, 0, stream>>>(out);
}

// Round 5
// 277.777 us; speedup vs baseline: 2.6784x; 1.3479x over previous
//
#include <hip/hip_runtime.h>
#include <hip/hip_bf16.h>
#include <math.h>

#define LYR 8
#define SEQ 4096
#define DIM 2048
#define NH 16
#define HD 128
#define NQ 32
#define NKV 256   // KVH*HD
#define NQE 2048  // H*HD

typedef __attribute__((ext_vector_type(8))) short short8;
typedef __attribute__((ext_vector_type(4))) float f32x4;

// workspace layout (float units)
#define WS_IRQ   0                        // 256
#define WS_ABLOB 256                      // 524288 floats = 1048576 shorts (A-frag blob for Q)
#define WS_COS   524544                   // 524288
#define WS_SIN   1048832                  // 524288
#define WS_QBUF  1573120                  // 524288  summed Q fp32 [l][q][2048]
#define WS_PART  2097408                  // 2097152 partials [ks4][l][q][2048]
#define WS_W2    4194560                  // 4194304 floats = 8388608 shorts (16MB)
#define WS_KBLOB 8388864                  // 8388608 floats = 16777216 shorts (32MB)
#define WS_QBLOB 16777472                 // 524288 floats = 1048576 shorts
// end 17301760 floats ~ 69.2 MB

__device__ __forceinline__ short f2bf(float x) {
  __hip_bfloat16 h = __float2bfloat16(x);
  return *(short*)&h;
}
__device__ __forceinline__ float bf2f(short s) {
  unsigned u = ((unsigned)(unsigned short)s) << 16;
  return __uint_as_float(u);
}

#define GLOAD16(srcp, dstp) \
  __builtin_amdgcn_global_load_lds( \
      (const __attribute__((address_space(1))) unsigned int*)(srcp), \
      (__attribute__((address_space(3))) unsigned int*)(dstp), 16, 0, 0)

// ---------------- prep: W' = ln_w*k_w -> frag-lane-linear bf16 hi/lo blob ----------------
__global__ __launch_bounds__(256) void prep_kernel(
    const float* __restrict__ ln_w, const float* __restrict__ k_w,
    short* __restrict__ W2) {
  int kb = blockIdx.x, l = blockIdx.y, t = threadIdx.x;
  const float* kwl = k_w + (size_t)l * DIM * NKV;
  const float* lnl = ln_w + l * DIM;
  short* blob = W2 + (size_t)(l * 64 + kb) * 16384;
  #pragma unroll
  for (int i = 0; i < 4; ++i) {
    int p = t + i * 256;
    int fi = p >> 6, lane = p & 63;
    int n = fi * 16 + (lane & 15);
    int k0 = kb * 32 + (lane >> 4) * 8;
    short hi8[8], lo8[8];
    #pragma unroll
    for (int e = 0; e < 8; ++e) {
      float v = lnl[k0 + e] * kwl[(size_t)(k0 + e) * NKV + n];
      short h = f2bf(v);
      hi8[e] = h;
      lo8[e] = f2bf(v - bf2f(h));
    }
    *(short8*)(blob + p * 8) = *(short8*)hi8;
    *(short8*)(blob + 8192 + p * 8) = *(short8*)lo8;
  }
}

// ---------------- rmsq: inv_rms for the 32 q rows ----------------
__global__ __launch_bounds__(256) void rmsq_kernel(const float* __restrict__ hs,
                                                   const int* __restrict__ q_idx,
                                                   float* __restrict__ irq) {
  int qi = blockIdx.x, l = blockIdx.y, t = threadIdx.x;
  int s = q_idx[qi];
  const float* row = hs + ((size_t)l * SEQ + s) * DIM;
  float4 v0 = *(const float4*)(row + t * 4);
  float4 v1 = *(const float4*)(row + t * 4 + 1024);
  float acc = v0.x*v0.x + v0.y*v0.y + v0.z*v0.z + v0.w*v0.w
            + v1.x*v1.x + v1.y*v1.y + v1.z*v1.z + v1.w*v1.w;
  #pragma unroll
  for (int off = 32; off >= 1; off >>= 1) acc += __shfl_down(acc, off);
  __shared__ float red[4];
  if ((t & 63) == 0) red[t >> 6] = acc;
  __syncthreads();
  if (t == 0) {
    float tot = red[0] + red[1] + red[2] + red[3];
    irq[l * NQ + qi] = rsqrtf(tot / (float)DIM + 1e-6f);
  }
}

// ---------------- cossin: mrope tables [S][HD] ----------------
__global__ void cossin_kernel(const int* __restrict__ pos_ids,
                              float* __restrict__ cost, float* __restrict__ sint) {
  int idx = blockIdx.x * 256 + threadIdx.x;
  int s = idx >> 7, d = idx & 127;
  int t = (d < 32) ? 0 : (d < 80 ? 1 : 2);
  int j = d & 63;
  double invf = pow(1000000.0, -(double)j / 64.0);
  double ph = (double)pos_ids[t * SEQ + s] * invf;
  cost[idx] = (float)cos(ph);
  sint[idx] = (float)sin(ph);
}

// ---------------- xqt: build A-frag blob for Q proj ----------------
// Ablob[l]: [kb=64][half=2][mf=2][lane64 x short8]; A[row=(lane&15)+mf*16][k=kb*32+(lane>>4)*8+e]
__global__ __launch_bounds__(256) void xqt_kernel(
    const float* __restrict__ hs, const float* __restrict__ ln_w,
    const int* __restrict__ q_idx, const float* __restrict__ irq,
    short* __restrict__ Ablob) {
  __shared__ int qix[32];
  __shared__ float qir[32];
  int l = blockIdx.x, t = threadIdx.x;
  if (t < 32) { qix[t] = q_idx[t]; qir[t] = irq[l * NQ + t]; }
  __syncthreads();
  int lane = t & 63, g4 = t >> 6;
  short* base = Ablob + (size_t)l * 131072;
  int row = lane & 15, kgl = lane >> 4;
  for (int i = 0; i < 64; ++i) {
    int group = g4 * 64 + i;                 // (kb, half, mf)
    int kb = group >> 2, half = (group >> 1) & 1, mf = group & 1;
    int r = row + mf * 16;
    int k0 = kb * 32 + kgl * 8;
    const float* src = hs + ((size_t)l * SEQ + qix[r]) * DIM + k0;
    const float* lnp = ln_w + l * DIM + k0;
    float ir = qir[r];
    float4 v0 = *(const float4*)src;
    float4 v1 = *(const float4*)(src + 4);
    float4 w0 = *(const float4*)lnp;
    float4 w1 = *(const float4*)(lnp + 4);
    float av[8] = {v0.x*w0.x, v0.y*w0.y, v0.z*w0.z, v0.w*w0.w,
                   v1.x*w1.x, v1.y*w1.y, v1.z*w1.z, v1.w*w1.w};
    short o8[8];
    #pragma unroll
    for (int e = 0; e < 8; ++e) {
      float v = av[e] * ir;
      short h = f2bf(v);
      o8[e] = half ? f2bf(v - bf2f(h)) : h;
    }
    *(short8*)(base + group * 512 + lane * 8) = *(short8*)o8;
  }
}

// ---------------- kgemm: K proj bf16x3 MFMA + RMSNorm + bias + RoPE + blob write ----------------
// BM=64 BN=256 BK=32, 256 thr = 4 waves (1m x 4n), 80KB LDS -> 2 blocks/CU
// A-prefetch distance 2 (register ping-pong), setprio around MFMA
__global__ __launch_bounds__(256) void kgemm_kernel(
    const float* __restrict__ hs, const short* __restrict__ W2,
    const float* __restrict__ k_b, const float* __restrict__ cost,
    const float* __restrict__ sint, short* __restrict__ Kblob) {
  __shared__ __align__(1024) char SM[81920];  // As 16KB | Bs 64KB ; reused as Kraw+irs

  int t = threadIdx.x;
  int fid = blockIdx.x;
  int l = fid & 7, sb = fid >> 3;
  int s0 = sb * 64;
  int lane = t & 63, w = t >> 6;
  int fr = lane & 15, kg = lane >> 4;
  int arow = t >> 2, akg = t & 3;

  const float* hrow = hs + ((size_t)l * SEQ + s0 + arow) * DIM + akg * 8;
  const char* wbase = (const char*)(W2 + (size_t)l * 64 * 16384);

  int amf = arow >> 4;
  int awoff = amf * 1024 + (((akg * 16 + (arow & 15)) * 16) ^ (akg << 5));
  int aroff = (lane * 16) ^ ((lane >> 4) << 5);

  f32x4 acc[4][4];
  #pragma unroll
  for (int mf = 0; mf < 4; ++mf)
    #pragma unroll
    for (int nf = 0; nf < 4; ++nf) acc[mf][nf] = (f32x4){0.f, 0.f, 0.f, 0.f};
  float sq = 0.f;
  float4 rA0, rA1, rB0, rB1;

  // prologue: B(0) -> buf0; A(0) -> cvt+write buf0; A(1) -> regs
  {
    #pragma unroll
    for (int c = 0; c < 8; ++c) {
      int chunk = w * 8 + c;
      GLOAD16(wbase + chunk * 1024 + lane * 16, SM + 16384 + chunk * 1024);
    }
    float4 a0 = *(const float4*)(hrow);
    float4 a1 = *(const float4*)(hrow + 4);
    float av[8] = {a0.x, a0.y, a0.z, a0.w, a1.x, a1.y, a1.z, a1.w};
    short hi8[8], lo8[8];
    #pragma unroll
    for (int e = 0; e < 8; ++e) {
      sq += av[e] * av[e];
      short h = f2bf(av[e]);
      hi8[e] = h;
      lo8[e] = f2bf(av[e] - bf2f(h));
    }
    *(short8*)(SM + awoff) = *(short8*)hi8;
    *(short8*)(SM + 4096 + awoff) = *(short8*)lo8;
    rA0 = *(const float4*)(hrow + 32);
    rA1 = *(const float4*)(hrow + 36);
  }
  __syncthreads();

#define KSTEP(KB, C0, C1, N0, N1) do { \
    int buf_ = (KB) & 1; \
    char* asb_ = SM + buf_ * 8192; \
    char* bsb_ = SM + 16384 + buf_ * 32768; \
    if ((KB) < 63) { \
      const char* src_ = wbase + (size_t)((KB) + 1) * 32768; \
      char* dst_ = SM + 16384 + (buf_ ^ 1) * 32768; \
      _Pragma("unroll") \
      for (int c = 0; c < 8; ++c) { \
        int chunk_ = w * 8 + c; \
        GLOAD16(src_ + chunk_ * 1024 + lane * 16, dst_ + chunk_ * 1024); \
      } \
    } \
    if ((KB) < 62) { \
      N0 = *(const float4*)(hrow + ((KB) + 2) * 32); \
      N1 = *(const float4*)(hrow + ((KB) + 2) * 32 + 4); \
    } \
    short8 ah_[4], al_[4]; \
    _Pragma("unroll") \
    for (int mf = 0; mf < 4; ++mf) { \
      ah_[mf] = *(const short8*)(asb_ + mf * 1024 + aroff); \
      al_[mf] = *(const short8*)(asb_ + 4096 + mf * 1024 + aroff); \
    } \
    __builtin_amdgcn_s_setprio(1); \
    _Pragma("unroll") \
    for (int nf = 0; nf < 4; ++nf) { \
      int f_ = w + nf * 4; \
      short8 bh_ = *(const short8*)(bsb_ + f_ * 1024 + lane * 16); \
      short8 bl_ = *(const short8*)(bsb_ + 16384 + f_ * 1024 + lane * 16); \
      _Pragma("unroll") \
      for (int mf = 0; mf < 4; ++mf) { \
        acc[mf][nf] = __builtin_amdgcn_mfma_f32_16x16x32_bf16(ah_[mf], bh_, acc[mf][nf], 0, 0, 0); \
        acc[mf][nf] = __builtin_amdgcn_mfma_f32_16x16x32_bf16(ah_[mf], bl_, acc[mf][nf], 0, 0, 0); \
        acc[mf][nf] = __builtin_amdgcn_mfma_f32_16x16x32_bf16(al_[mf], bh_, acc[mf][nf], 0, 0, 0); \
      } \
    } \
    __builtin_amdgcn_s_setprio(0); \
    if ((KB) < 63) { \
      char* asn_ = SM + (buf_ ^ 1) * 8192; \
      float av_[8] = {C0.x, C0.y, C0.z, C0.w, C1.x, C1.y, C1.z, C1.w}; \
      short hi8_[8], lo8_[8]; \
      _Pragma("unroll") \
      for (int e = 0; e < 8; ++e) { \
        sq += av_[e] * av_[e]; \
        short h_ = f2bf(av_[e]); \
        hi8_[e] = h_; \
        lo8_[e] = f2bf(av_[e] - bf2f(h_)); \
      } \
      *(short8*)(asn_ + awoff) = *(short8*)hi8_; \
      *(short8*)(asn_ + 4096 + awoff) = *(short8*)lo8_; \
    } \
    __syncthreads(); \
  } while (0)

  for (int kb2 = 0; kb2 < 32; ++kb2) {
    KSTEP(2 * kb2, rA0, rA1, rB0, rB1);
    KSTEP(2 * kb2 + 1, rB0, rB1, rA0, rA1);
  }
#undef KSTEP

  // ---- epilogue ----
  sq += __shfl_xor(sq, 1);
  sq += __shfl_xor(sq, 2);
  float* irs = (float*)(SM + 66560);
  if ((t & 3) == 0) irs[arow] = rsqrtf(sq / (float)DIM + 1e-6f);
  __syncthreads();

  float* Kraw = (float*)SM;
  int j = w * 16 + fr;
  float bias0 = k_b[l * NKV + j];
  float bias1 = k_b[l * NKV + j + 64];
  float bias2 = k_b[l * NKV + j + 128];
  float bias3 = k_b[l * NKV + j + 192];
  #pragma unroll
  for (int mf = 0; mf < 4; ++mf) {
    #pragma unroll
    for (int r = 0; r < 4; ++r) {
      int row = mf * 16 + kg * 4 + r;
      int s = s0 + row;
      float ir = irs[row];
      float v0 = acc[mf][0][r] * ir + bias0;
      float v1 = acc[mf][1][r] * ir + bias1;
      float v2 = acc[mf][2][r] * ir + bias2;
      float v3 = acc[mf][3][r] * ir + bias3;
      float cj = cost[s * HD + j], sj = sint[s * HD + j];
      float cj2 = cost[s * HD + j + 64], sj2 = sint[s * HD + j + 64];
      float* kr = Kraw + row * 260;
      kr[j]       = v0 * cj - v1 * sj;
      kr[j + 64]  = v1 * cj2 + v0 * sj2;
      kr[j + 128] = v2 * cj - v3 * sj;
      kr[j + 192] = v3 * cj2 + v2 * sj2;
    }
  }
  __syncthreads();

  int kc = sb >> 1, fb = (sb & 1) * 4;
  #pragma unroll
  for (int i = 0; i < 8; ++i) {
    int c = t + i * 256;
    int lc = c & 63, fl = (c >> 6) & 3, ts = (c >> 8) & 3, kv = c >> 10;
    int key = fl * 16 + (lc & 15);
    int d0 = kv * 128 + ts * 32 + (lc >> 4) * 8;
    float4 x0 = *(const float4*)(Kraw + key * 260 + d0);
    float4 x1 = *(const float4*)(Kraw + key * 260 + d0 + 4);
    float av[8] = {x0.x, x0.y, x0.z, x0.w, x1.x, x1.y, x1.z, x1.w};
    short hi8[8], lo8[8];
    #pragma unroll
    for (int e = 0; e < 8; ++e) {
      short h = f2bf(av[e]);
      hi8[e] = h;
      lo8[e] = f2bf(av[e] - bf2f(h));
    }
    short* bb = Kblob + (size_t)((l * 2 + kv) * 32 + kc) * 32768
              + (size_t)((ts * 2 + 0) * 8 + fb + fl) * 512 + lc * 8;
    *(short8*)bb = *(short8*)hi8;
    *(short8*)(bb + 4096) = *(short8*)lo8;
  }
}

// ---------------- qgemm: Q = xq . q_w via bf16x3 MFMA, q_w streamed fp32 ----------------
// grid (nc=8, ks=4, l=8), 512 thr = 8 waves; LDS: Atile 64KB + B dbuf 64KB
__global__ __launch_bounds__(512) void qgemm_kernel(
    const float* __restrict__ q_w, const short* __restrict__ Ablob,
    float* __restrict__ part) {
  __shared__ __align__(1024) char SM[131072];
  int t = threadIdx.x;
  int nc = blockIdx.x, ks = blockIdx.y, l = blockIdx.z;
  int lane = t & 63, w = t >> 6;
  int fr = lane & 15, kg = lane >> 4;
  const char* abase = (const char*)(Ablob + (size_t)l * 131072 + (size_t)ks * 32768);
  const float* qwl = q_w + (size_t)l * DIM * NQE;

  // prologue: stage Atile (64KB) + B tile 0
  #pragma unroll
  for (int c = 0; c < 8; ++c) {
    int chunk = w * 8 + c;
    GLOAD16(abase + chunk * 1024 + lane * 16, SM + chunk * 1024);
  }
  #pragma unroll
  for (int c = 0; c < 4; ++c) {
    int r = w * 4 + c;
    GLOAD16((const char*)(qwl + (size_t)(ks * 512 + r) * NQE + nc * 256) + lane * 16,
            SM + 65536 + r * 1024 + lane * 16);
  }
  f32x4 acc[2][2];
  #pragma unroll
  for (int mf = 0; mf < 2; ++mf)
    #pragma unroll
    for (int nf = 0; nf < 2; ++nf) acc[mf][nf] = (f32x4){0.f, 0.f, 0.f, 0.f};
  __syncthreads();

  for (int ts = 0; ts < 16; ++ts) {
    int buf = ts & 1;
    if (ts < 15) {
      #pragma unroll
      for (int c = 0; c < 4; ++c) {
        int r = w * 4 + c;
        GLOAD16((const char*)(qwl + (size_t)(ks * 512 + (ts + 1) * 32 + r) * NQE + nc * 256) + lane * 16,
                SM + 65536 + (buf ^ 1) * 32768 + r * 1024 + lane * 16);
      }
    }
    short8 ah[2], al[2];
    #pragma unroll
    for (int mf = 0; mf < 2; ++mf) {
      ah[mf] = *(const short8*)(SM + ts * 4096 + mf * 1024 + lane * 16);
      al[mf] = *(const short8*)(SM + ts * 4096 + 2048 + mf * 1024 + lane * 16);
    }
    const float* bt = (const float*)(SM + 65536 + buf * 32768);
    #pragma unroll
    for (int nf = 0; nf < 2; ++nf) {
      int c = w * 32 + nf * 16 + fr;
      short bh8[8], bl8[8];
      #pragma unroll
      for (int e = 0; e < 8; ++e) {
        float v = bt[(kg * 8 + e) * 256 + c];
        short h = f2bf(v);
        bh8[e] = h;
        bl8[e] = f2bf(v - bf2f(h));
      }
      short8 bh = *(short8*)bh8, bl = *(short8*)bl8;
      #pragma unroll
      for (int mf = 0; mf < 2; ++mf) {
        acc[mf][nf] = __builtin_amdgcn_mfma_f32_16x16x32_bf16(ah[mf], bh, acc[mf][nf], 0, 0, 0);
        acc[mf][nf] = __builtin_amdgcn_mfma_f32_16x16x32_bf16(ah[mf], bl, acc[mf][nf], 0, 0, 0);
        acc[mf][nf] = __builtin_amdgcn_mfma_f32_16x16x32_bf16(al[mf], bh, acc[mf][nf], 0, 0, 0);
      }
    }
    __syncthreads();
  }

  // epilogue: partials [ks][l][q32][2048]
  #pragma unroll
  for (int mf = 0; mf < 2; ++mf) {
    #pragma unroll
    for (int r = 0; r < 4; ++r) {
      int row = mf * 16 + kg * 4 + r;
      float* prow = part + ((size_t)((ks * LYR + l) * NQ + row)) * NQE + nc * 256;
      #pragma unroll
      for (int nf = 0; nf < 2; ++nf) {
        int col = w * 32 + nf * 16 + fr;
        prow[col] = acc[mf][nf][r];
      }
    }
  }
}

// ---------------- qred: sum 4 k-split partials + bias -> Qbuf ----------------
__global__ __launch_bounds__(256) void qred_kernel(
    const float* __restrict__ part, const float* __restrict__ q_b,
    float* __restrict__ Qbuf) {
  int idx = blockIdx.x * 256 + threadIdx.x;  // L*NQ*NQE = 524288
  int n = idx & 2047, q = (idx >> 11) & 31, l = idx >> 16;
  float v = q_b[l * NQE + n];
  #pragma unroll
  for (int ks = 0; ks < 4; ++ks)
    v += part[((size_t)((ks * LYR + l) * NQ + q)) * NQE + n];
  Qbuf[((size_t)l * NQ + q) * NQE + n] = v;
}

// ---------------- qpack: rope Q + split to frag-lane-linear blob ----------------
__global__ __launch_bounds__(256) void qpack_kernel(
    const float* __restrict__ Qbuf, const float* __restrict__ cost,
    const float* __restrict__ sint, const int* __restrict__ q_idx,
    short* __restrict__ Qblob) {
  int kv = blockIdx.x, l = blockIdx.y, t = threadIdx.x;
  short* blob = Qblob + (size_t)(l * 2 + kv) * 65536;
  #pragma unroll
  for (int i = 0; i < 16; ++i) {
    int p = t + i * 256;               // [ts4][f16][lane64]
    int ts = p >> 10, f = (p >> 6) & 15, lane = p & 63;
    int row = f * 16 + (lane & 15);
    int hh = row >> 5, q = row & 31;
    int h = kv * 8 + hh;
    int d0 = ts * 32 + (lane >> 4) * 8;
    int s = q_idx[q];
    const float* qrow = Qbuf + ((size_t)l * NQ + q) * NQE + h * HD;
    const float* ct = cost + s * HD;
    const float* st = sint + s * HD;
    short hi8[8], lo8[8];
    #pragma unroll
    for (int e = 0; e < 8; ++e) {
      int d = d0 + e;
      float x = qrow[d];
      float xp = qrow[d ^ 64];
      float v = (d < 64) ? (x * ct[d] - xp * st[d]) : (x * ct[d] + xp * st[d]);
      short h2 = f2bf(v);
      hi8[e] = h2;
      lo8[e] = f2bf(v - bf2f(h2));
    }
    *(short8*)(blob + ((ts * 2 + 0) * 16 + f) * 512 + lane * 8) = *(short8*)hi8;
    *(short8*)(blob + ((ts * 2 + 1) * 16 + f) * 512 + lane * 8) = *(short8*)lo8;
  }
}

// ---------------- scores: bf16x3 MFMA, M=256 (8 heads x 32 q) x 128 keys ----------------
__global__ __launch_bounds__(512) void scores_kernel(
    const short* __restrict__ Qblob, const short* __restrict__ Kblob,
    const int* __restrict__ q_idx, float* __restrict__ out) {
  __shared__ short Qs[2][16384];
  __shared__ short Ks[2][8192];
  __shared__ int qiv[32];
  int t = threadIdx.x;
  int kc = blockIdx.x, kv = blockIdx.y, l = blockIdx.z;
  int lane = t & 63, w = t >> 6;
  int wm = w >> 1, wn = w & 1;
  if (t < 32) qiv[t] = q_idx[t];
  const char* qsrc = (const char*)(Qblob + (size_t)(l * 2 + kv) * 65536);
  const char* ksrc = (const char*)(Kblob + (size_t)((l * 2 + kv) * 32 + kc) * 32768);
  #pragma unroll
  for (int c = 0; c < 4; ++c) {
    int off = (w * 4 + c) * 1024;
    GLOAD16(qsrc + off + lane * 16, (char*)Qs[0] + off);
  }
  #pragma unroll
  for (int c = 0; c < 2; ++c) {
    int off = (w * 2 + c) * 1024;
    GLOAD16(ksrc + off + lane * 16, (char*)Ks[0] + off);
  }
  f32x4 acc[4][4];
  #pragma unroll
  for (int mf = 0; mf < 4; ++mf)
    #pragma unroll
    for (int nf = 0; nf < 4; ++nf) acc[mf][nf] = (f32x4){0.f, 0.f, 0.f, 0.f};
  __syncthreads();
  for (int ts = 0; ts < 4; ++ts) {
    int buf = ts & 1;
    if (ts < 3) {
      const char* qs = qsrc + (ts + 1) * 32768;
      const char* ks = ksrc + (ts + 1) * 16384;
      #pragma unroll
      for (int c = 0; c < 4; ++c) {
        int off = (w * 4 + c) * 1024;
        GLOAD16(qs + off + lane * 16, (char*)Qs[(ts + 1) & 1] + off);
      }
      #pragma unroll
      for (int c = 0; c < 2; ++c) {
        int off = (w * 2 + c) * 1024;
        GLOAD16(ks + off + lane * 16, (char*)Ks[(ts + 1) & 1] + off);
      }
    }
    short8 ah[4], al[4];
    #pragma unroll
    for (int mf = 0; mf < 4; ++mf) {
      int f = wm * 4 + mf;
      ah[mf] = *(const short8*)(Qs[buf] + f * 512 + lane * 8);
      al[mf] = *(const short8*)(Qs[buf] + 8192 + f * 512 + lane * 8);
    }
    #pragma unroll
    for (int nf = 0; nf < 4; ++nf) {
      int f = wn * 4 + nf;
      short8 bh = *(const short8*)(Ks[buf] + f * 512 + lane * 8);
      short8 bl = *(const short8*)(Ks[buf] + 4096 + f * 512 + lane * 8);
      #pragma unroll
      for (int mf = 0; mf < 4; ++mf) {
        acc[mf][nf] = __builtin_amdgcn_mfma_f32_16x16x32_bf16(ah[mf], bh, acc[mf][nf], 0, 0, 0);
        acc[mf][nf] = __builtin_amdgcn_mfma_f32_16x16x32_bf16(ah[mf], bl, acc[mf][nf], 0, 0, 0);
        acc[mf][nf] = __builtin_amdgcn_mfma_f32_16x16x32_bf16(al[mf], bh, acc[mf][nf], 0, 0, 0);
      }
    }
    __syncthreads();
  }
  const float scale = 0.088388347648318447f;
  #pragma unroll
  for (int mf = 0; mf < 4; ++mf) {
    #pragma unroll
    for (int r = 0; r < 4; ++r) {
      int rr = wm * 64 + mf * 16 + (lane >> 4) * 4 + r;
      int hh = rr >> 5, q = rr & 31;
      int qv = qiv[q];
      float* orow = out + (((size_t)(l * NH + kv * 8 + hh)) * NQ + q) * SEQ;
      #pragma unroll
      for (int nf = 0; nf < 4; ++nf) {
        int key = kc * 128 + (wn * 4 + nf) * 16 + (lane & 15);
        orow[key] = (key > qv) ? -1e9f : acc[mf][nf][r] * scale;
      }
    }
  }
}

// ---------------- softmax over S ----------------
__global__ __launch_bounds__(256) void softmax_kernel(float* __restrict__ out) {
  size_t row = blockIdx.x;
  float* p = out + row * SEQ;
  int t = threadIdx.x;
  float4 v[4];
  float mx = -1e30f;
  #pragma unroll
  for (int i = 0; i < 4; ++i) {
    v[i] = *(const float4*)(p + t * 4 + i * 1024);
    mx = fmaxf(mx, fmaxf(fmaxf(v[i].x, v[i].y), fmaxf(v[i].z, v[i].w)));
  }
  #pragma unroll
  for (int off = 32; off >= 1; off >>= 1) mx = fmaxf(mx, __shfl_xor(mx, off));
  __shared__ float red[4];
  if ((t & 63) == 0) red[t >> 6] = mx;
  __syncthreads();
  mx = fmaxf(fmaxf(red[0], red[1]), fmaxf(red[2], red[3]));
  __syncthreads();
  float sum = 0.f;
  #pragma unroll
  for (int i = 0; i < 4; ++i) {
    v[i].x = __expf(v[i].x - mx); v[i].y = __expf(v[i].y - mx);
    v[i].z = __expf(v[i].z - mx); v[i].w = __expf(v[i].w - mx);
    sum += v[i].x + v[i].y + v[i].z + v[i].w;
  }
  #pragma unroll
  for (int off = 32; off >= 1; off >>= 1) sum += __shfl_xor(sum, off);
  if ((t & 63) == 0) red[t >> 6] = sum;
  __syncthreads();
  sum = red[0] + red[1] + red[2] + red[3];
  float inv = 1.f / sum;
  #pragma unroll
  for (int i = 0; i < 4; ++i) {
    v[i].x *= inv; v[i].y *= inv; v[i].z *= inv; v[i].w *= inv;
    *(float4*)(p + t * 4 + i * 1024) = v[i];
  }
}

extern "C" void kernel_launch(void* const* d_in, const int* in_sizes, int n_in,
                              void* d_out, int out_size, void* d_ws, size_t ws_size,
                              hipStream_t stream) {
  const float* hs   = (const float*)d_in[0];
  const float* ln_w = (const float*)d_in[1];
  const float* q_w  = (const float*)d_in[2];
  const float* q_b  = (const float*)d_in[3];
  const float* k_w  = (const float*)d_in[4];
  const float* k_b  = (const float*)d_in[5];
  const int* pos    = (const int*)d_in[6];
  const int* qidx   = (const int*)d_in[7];
  float* out = (float*)d_out;
  float* ws = (float*)d_ws;
  float* irq   = ws + WS_IRQ;
  short* Ablob = (short*)(ws + WS_ABLOB);
  float* cost  = ws + WS_COS;
  float* sint  = ws + WS_SIN;
  float* Qbuf  = ws + WS_QBUF;
  float* part  = ws + WS_PART;
  short* W2    = (short*)(ws + WS_W2);
  short* Kblob = (short*)(ws + WS_KBLOB);
  short* Qblob = (short*)(ws + WS_QBLOB);

  prep_kernel<<<dim3(64, LYR), 256, 0, stream>>>(ln_w, k_w, W2);
  rmsq_kernel<<<dim3(NQ, LYR), 256, 0, stream>>>(hs, qidx, irq);
  cossin_kernel<<<(SEQ * HD) / 256, 256, 0, stream>>>(pos, cost, sint);
  xqt_kernel<<<LYR, 256, 0, stream>>>(hs, ln_w, qidx, irq, Ablob);
  kgemm_kernel<<<512, 256, 0, stream>>>(hs, W2, k_b, cost, sint, Kblob);
  qgemm_kernel<<<dim3(8, 4, LYR), 512, 0, stream>>>(q_w, Ablob, part);
  qred_kernel<<<2048, 256, 0, stream>>>(part, q_b, Qbuf);
  qpack_kernel<<<dim3(2, LYR), 256, 0, stream>>>(Qbuf, cost, sint, qidx, Qblob);
  scores_kernel<<<dim3(32, 2, LYR), 512, 0, stream>>>(Qblob, Kblob, qidx, out);
  softmax_kernel<<<LYR * NH * NQ, 256, 0, stream>>>(out);
}